// Round 6
// baseline (983.022 us; speedup 1.0000x reference)
//
#include <hip/hip_runtime.h>
#include <hip/hip_bf16.h>

#define B_   2
#define T_   2048
#define D_   2048
#define H_   16
#define DH_  128
#define DFF_ 8192

typedef __attribute__((ext_vector_type(8))) short bf16x8;
typedef __attribute__((ext_vector_type(4))) float f32x4;

__device__ __forceinline__ short f2bf(float f) {
    __hip_bfloat16 h = __float2bfloat16(f);
    return *reinterpret_cast<short*>(&h);
}

__device__ __forceinline__ void gload_lds16(const void* g, void* l) {
    __builtin_amdgcn_global_load_lds(
        (const __attribute__((address_space(1))) void*)g,
        (__attribute__((address_space(3))) void*)l,
        16, 0, 0);
}

__device__ __forceinline__ float gelu_tanh(float x) {
    float x3 = x * x * x;
    return 0.5f * x * (1.f + tanhf(0.7978845608028654f * (x + 0.044715f * x3)));
}

#define MFMA32(a, b, c) __builtin_amdgcn_mfma_f32_16x16x32_bf16((a), (b), (c), 0, 0, 0)

// ---------------------------------------------------------------------------
// Transpose + f32->bf16 convert (unchanged)
// ---------------------------------------------------------------------------
__global__ __launch_bounds__(256) void transpose_cvt(const float* __restrict__ in,
                                                     __hip_bfloat16* __restrict__ out,
                                                     int K, int N, int out_ld, int out_row0)
{
    __shared__ float t[32][65];
    const int n0 = blockIdx.x * 64, k0 = blockIdx.y * 32;
    const int tid = threadIdx.x;
    {
        int kr = tid >> 4;
        int nc = (tid & 15) * 4;
        const float* src = in + (size_t)(k0 + kr) * N + n0 + nc;
        float4 a = *reinterpret_cast<const float4*>(src);
        float4 b = *reinterpret_cast<const float4*>(src + (size_t)16 * N);
        t[kr][nc] = a.x; t[kr][nc + 1] = a.y; t[kr][nc + 2] = a.z; t[kr][nc + 3] = a.w;
        t[kr + 16][nc] = b.x; t[kr + 16][nc + 1] = b.y; t[kr + 16][nc + 2] = b.z; t[kr + 16][nc + 3] = b.w;
    }
    __syncthreads();
    {
        int n  = tid >> 2;
        int kc = (tid & 3) * 8;
        __hip_bfloat16 ob[8];
#pragma unroll
        for (int j = 0; j < 8; ++j) ob[j] = __float2bfloat16(t[kc + j][n]);
        *reinterpret_cast<uint4*>(out + (size_t)(out_row0 + n0 + n) * out_ld + k0 + kc) =
            *reinterpret_cast<uint4*>(ob);
    }
}

// ---------------------------------------------------------------------------
// LayerNorm (unchanged)
// ---------------------------------------------------------------------------
__global__ __launch_bounds__(256) void ln_kernel(const float* __restrict__ x,
                                                 const float* __restrict__ sc,
                                                 const float* __restrict__ of,
                                                 __hip_bfloat16* __restrict__ out)
{
    int row = blockIdx.x, tid = threadIdx.x;
    const float* xr = x + (size_t)row * D_;
    float4 v0 = reinterpret_cast<const float4*>(xr)[tid * 2];
    float4 v1 = reinterpret_cast<const float4*>(xr)[tid * 2 + 1];
    float vv[8] = {v0.x, v0.y, v0.z, v0.w, v1.x, v1.y, v1.z, v1.w};
    float s = 0.f, ss = 0.f;
#pragma unroll
    for (int j = 0; j < 8; ++j) { s += vv[j]; ss += vv[j] * vv[j]; }
    for (int o = 32; o; o >>= 1) { s += __shfl_down(s, o); ss += __shfl_down(ss, o); }
    __shared__ float red[8];
    int wid = tid >> 6, lane = tid & 63;
    if (!lane) { red[wid] = s; red[4 + wid] = ss; }
    __syncthreads();
    s  = red[0] + red[1] + red[2] + red[3];
    ss = red[4] + red[5] + red[6] + red[7];
    float mean = s * (1.f / D_);
    float var  = ss * (1.f / D_) - mean * mean;
    float rstd = rsqrtf(var + 1e-5f);
    int c0 = tid * 8;
    __hip_bfloat16 ob[8];
#pragma unroll
    for (int j = 0; j < 8; ++j)
        ob[j] = __float2bfloat16((vv[j] - mean) * rstd * sc[c0 + j] + of[c0 + j]);
    *reinterpret_cast<uint4*>(out + (size_t)row * D_ + c0) = *reinterpret_cast<uint4*>(ob);
}

// ---------------------------------------------------------------------------
// Fat-wave GEMM. Tile BM x 256, BK=64 (2 k-slices of 32). 256 threads =
// 4 waves (2M x 2N); per-wave output (BM/2) x 128, acc[MFR][8].
// flop/LDS-byte doubled vs r3-r5: per CU per K-tile LDS reads = 4w x 4*MFR
// b128 = (BM=256: 1536cy) vs MFMA 2480cy -> MFMA-bound.
// Monolithic schedule: no intra-tile barriers (waves drift; compiler
// interleaves ds_read under MFMA with fine lgkmcnt); prefetch t+1 issued at
// tile top (~2300cy cover >> 900cy HBM latency) so the __syncthreads drain
// at tile end is near-free. LDS 64B rows, slot swizzle hi^((lo>>1)&3)
// (verified 0 conflicts r5), inverse pre-swizzle on global source.
// EPI: 0 bf16 out; 1 f32+resid; 2 bf16+bias+gelu; 3 f32+bias+resid
// ---------------------------------------------------------------------------
template<int EPI, int BM>
__global__ __launch_bounds__(256, 1) void gemmW(
    const __hip_bfloat16* __restrict__ A, const __hip_bfloat16* __restrict__ BT,
    void* __restrict__ Cout, const float* __restrict__ bias,
    const float* __restrict__ resid, int M, int N, int K)
{
    constexpr int MFR = BM / 32;        // per-wave m-frags (8 or 4)
    constexpr int AR  = BM / 64;        // A staging rounds per ks (4 or 2)
    __shared__ short As[2 * 2 * BM * 32];    // [buf][ks][row][32]
    __shared__ short Bs[2 * 2 * 256 * 32];

    const int tid = threadIdx.x;
    const int wid = tid >> 6, lane = tid & 63;
    const int lo = lane & 15, hi = lane >> 4;
    const int wr = wid >> 1, wc = wid & 1;

    // bijective XCD swizzle (all grids have nwg % 8 == 0)
    const int gx = gridDim.x;
    const int nwg = gx * gridDim.y;
    const int bid = blockIdx.y * gx + blockIdx.x;
    const int swz = (bid & 7) * (nwg >> 3) + (bid >> 3);
    const int m0 = (swz / gx) * BM, n0 = (swz % gx) * 256;

    // stage tile tt into buffer bsel (A: AR rounds/ks, B: 4 rounds/ks).
    // round covers 64 rows; thread -> (row = c>>2, 16B slot = c&3); source
    // k-column pre-swizzled by the read-side XOR (both-sides rule).
    auto stage = [&](int tt, int bsel) {
#pragma unroll
        for (int ks = 0; ks < 2; ++ks) {
#pragma unroll
            for (int l = 0; l < AR; ++l) {
                int c = l * 256 + tid;
                int row = c >> 2, ksub = c & 3;
                int kc = tt * 64 + ks * 32 + ((ksub ^ ((row >> 1) & 3)) << 3);
                gload_lds16(A + (size_t)(m0 + row) * K + kc,
                            (char*)As + (bsel * 2 + ks) * (BM * 64) + (l * 256 + wid * 64) * 16);
            }
#pragma unroll
            for (int l = 0; l < 4; ++l) {
                int c = l * 256 + tid;
                int row = c >> 2, ksub = c & 3;
                int kc = tt * 64 + ks * 32 + ((ksub ^ ((row >> 1) & 3)) << 3);
                gload_lds16(BT + (size_t)(n0 + row) * K + kc,
                            (char*)Bs + (bsel * 2 + ks) * 16384 + (l * 256 + wid * 64) * 16);
            }
        }
    };

    const int fsw = (hi ^ ((lo >> 1) & 3)) << 4;   // frag slot swizzle (bytes)
    f32x4 acc[MFR][8] = {};
    const int NT = K >> 6;

    stage(0, 0);
    __syncthreads();

    for (int t = 0; t < NT; ++t) {
        const int buf = t & 1;
        if (t + 1 < NT) stage(t + 1, buf ^ 1);

#pragma unroll
        for (int ks = 0; ks < 2; ++ks) {
            const char* Ab = (const char*)As + (buf * 2 + ks) * (BM * 64);
            const char* Bb = (const char*)Bs + (buf * 2 + ks) * 16384;
            bf16x8 bfr[8];
#pragma unroll
            for (int n = 0; n < 8; ++n)
                bfr[n] = *reinterpret_cast<const bf16x8*>(
                    Bb + (wc * 128 + n * 16 + lo) * 64 + fsw);
#pragma unroll
            for (int m = 0; m < MFR; ++m) {
                bf16x8 a = *reinterpret_cast<const bf16x8*>(
                    Ab + (wr * (BM / 2) + m * 16 + lo) * 64 + fsw);
                __builtin_amdgcn_s_setprio(1);
#pragma unroll
                for (int n = 0; n < 8; ++n)
                    acc[m][n] = MFMA32(a, bfr[n], acc[m][n]);
                __builtin_amdgcn_s_setprio(0);
            }
        }
        __syncthreads();   // t+1 staged ~full tile ago -> drain is cheap
    }

    // ---- epilogue
    float* Cf = (float*)Cout;
    __hip_bfloat16* Cb = (__hip_bfloat16*)Cout;
#pragma unroll
    for (int m = 0; m < MFR; ++m) {
        int rbase = m0 + wr * (BM / 2) + m * 16 + hi * 4;
#pragma unroll
        for (int n = 0; n < 8; ++n) {
            int col = n0 + wc * 128 + n * 16 + lo;
            float bv = (EPI == 2 || EPI == 3) ? bias[col] : 0.f;
#pragma unroll
            for (int i = 0; i < 4; ++i) {
                size_t idx = (size_t)(rbase + i) * N + col;
                float v = acc[m][n][i];
                if (EPI == 2 || EPI == 3) v += bv;
                if (EPI == 2) v = gelu_tanh(v);
                if (EPI == 1 || EPI == 3) v += resid[idx];
                if (EPI == 0 || EPI == 2) Cb[idx] = __float2bfloat16(v);
                else                      Cf[idx] = v;
            }
        }
    }
}

// ---------------------------------------------------------------------------
// RoPE (unchanged)
// ---------------------------------------------------------------------------
__global__ __launch_bounds__(256) void rope_kernel(__hip_bfloat16* __restrict__ qkv)
{
    int idx = blockIdx.x * 256 + threadIdx.x;
    int p  = idx & 31;
    int h  = (idx >> 5) & (H_ - 1);
    int bt = idx >> 9;
    int t  = bt & (T_ - 1);
    float invf = exp2f((float)p * -0.4152410118609203f);
    float fr = (float)t * invf;
    float cs, sn;
    __sincosf(fr, &sn, &cs);
    size_t base = (size_t)bt * (3 * D_) + h * DH_ + 2 * p;
#pragma unroll
    for (int qk = 0; qk < 2; ++qk) {
        uint* pp = reinterpret_cast<uint*>(qkv + base + qk * D_);
        uint u = *pp;
        float x1 = __uint_as_float(u << 16);
        float x2 = __uint_as_float(u & 0xffff0000u);
        short r0 = f2bf(x1 * cs - x2 * sn);
        short r1 = f2bf(x2 * cs + x1 * sn);
        *pp = ((uint)(unsigned short)r0) | (((uint)(unsigned short)r1) << 16);
    }
}

// ---------------------------------------------------------------------------
// Causal flash attention (r4/r5 version, unchanged — passed twice)
// ---------------------------------------------------------------------------
__global__ __launch_bounds__(256) void attn_kernel(const __hip_bfloat16* __restrict__ qkv,
                                                   __hip_bfloat16* __restrict__ ctx)
{
    constexpr int LDQ = 3 * D_;
    constexpr int SV  = 68;
    constexpr int SP  = 68;

    int idx = blockIdx.y * 32 + blockIdx.x;
    int swz = (idx & 7) * 128 + (idx >> 3);
    const int bh  = swz >> 5;
    const int bxr = 31 - (swz & 31);
    const int b = bh >> 4, h = bh & 15;
    const int tq0 = bxr * 64;

    const int tid = threadIdx.x, wid = tid >> 6, lane = tid & 63;
    const int lo = lane & 15, hi = lane >> 4;
    const int t0 = tq0 + wid * 16;

    __shared__ short Ks[2][64 * 128];
    __shared__ short VsT[128 * SV];
    __shared__ short Ps[4][16 * SP];

    const __hip_bfloat16* qrow = qkv + (size_t)(b * T_ + t0 + lo) * LDQ + h * DH_;
    bf16x8 qf[4];
#pragma unroll
    for (int dk = 0; dk < 4; ++dk)
        qf[dk] = *reinterpret_cast<const bf16x8*>(qrow + dk * 32 + hi * 8);

    f32x4 octx[8] = {};
    float mreg[4] = {-1e30f, -1e30f, -1e30f, -1e30f};
    float lreg[4] = {0.f, 0.f, 0.f, 0.f};

    const size_t kvrow0 = (size_t)(b * T_) * LDQ + h * DH_;
    const int nst = bxr + 1;

    const int kc = wid * 256 + lane;
    bf16x8 vr[4];

#define STAGE_K(s0v, buf)                                                     \
    do {                                                                      \
        _Pragma("unroll")                                                     \
        for (int i = 0; i < 4; ++i) {                                         \
            int c    = kc + i * 64;                                           \
            int sr   = c >> 4;                                                \
            int cbs  = ((c & 15) * 16) ^ ((sr & 7) << 4);                     \
            gload_lds16(qkv + kvrow0 + (size_t)((s0v) + sr) * LDQ + D_ + (cbs >> 1), \
                        &Ks[buf][(kc + i * 64) * 8]);                         \
        }                                                                     \
    } while (0)

#define LOAD_V(s0v)                                                           \
    do {                                                                      \
        _Pragma("unroll")                                                     \
        for (int it = 0; it < 4; ++it) {                                      \
            int c = it * 256 + tid;                                           \
            int s = c >> 4, dc = c & 15;                                      \
            vr[it] = *reinterpret_cast<const bf16x8*>(                        \
                qkv + kvrow0 + (size_t)((s0v) + s) * LDQ + 2 * D_ + dc * 8);  \
        }                                                                     \
    } while (0)

    STAGE_K(0, 0);
    LOAD_V(0);

    for (int st = 0; st < nst; ++st) {
        const int s0 = st * 64;
        const int cur = st & 1;
        __syncthreads();

#pragma unroll
        for (int it = 0; it < 4; ++it) {
            int c = it * 256 + tid;
            int s = c >> 4, dc = c & 15;
            int sswz = s ^ ((dc & 15) << 2);
            short* dst = &VsT[(dc * 8) * SV + sswz];
#pragma unroll
            for (int j = 0; j < 8; ++j)
                dst[j * SV] = vr[it][j];
        }
        if (st + 1 < nst) {
            STAGE_K(s0 + 64, cur ^ 1);
            LOAD_V(s0 + 64);
        }
        asm volatile("s_waitcnt lgkmcnt(0)" ::: "memory");
        __builtin_amdgcn_s_barrier();
        __builtin_amdgcn_sched_barrier(0);

        f32x4 sfr[4] = {};
        __builtin_amdgcn_s_setprio(1);
#pragma unroll
        for (int f = 0; f < 4; ++f) {
            int srow = f * 16 + lo;
            int sw = (srow & 7) << 4;
#pragma unroll
            for (int dk = 0; dk < 4; ++dk) {
                bf16x8 kf = *reinterpret_cast<const bf16x8*>(
                    (const char*)&Ks[cur][0] + srow * 256 + ((dk * 64 + hi * 16) ^ sw));
                sfr[f] = MFMA32(qf[dk], kf, sfr[f]);
            }
        }
        __builtin_amdgcn_s_setprio(0);

        const float qsc = 0.08838834764831845f;
#pragma unroll
        for (int f = 0; f < 4; ++f)
#pragma unroll
            for (int i = 0; i < 4; ++i)
                sfr[f][i] *= qsc;
        if (st == nst - 1) {
#pragma unroll
            for (int f = 0; f < 4; ++f)
#pragma unroll
                for (int i = 0; i < 4; ++i)
                    if (s0 + f * 16 + lo > t0 + hi * 4 + i) sfr[f][i] = -1e30f;
        }

        float ps[4];
#pragma unroll
        for (int i = 0; i < 4; ++i) {
            float v = fmaxf(fmaxf(sfr[0][i], sfr[1][i]), fmaxf(sfr[2][i], sfr[3][i]));
            v = fmaxf(v, __shfl_xor(v, 1));
            v = fmaxf(v, __shfl_xor(v, 2));
            v = fmaxf(v, __shfl_xor(v, 4));
            v = fmaxf(v, __shfl_xor(v, 8));
            float mn = fmaxf(mreg[i], v);
            ps[i] = __expf(mreg[i] - mn);
            mreg[i] = mn;
        }
#pragma unroll
        for (int f = 0; f < 4; ++f)
#pragma unroll
            for (int i = 0; i < 4; ++i)
                sfr[f][i] = __expf(sfr[f][i] - mreg[i]);
#pragma unroll
        for (int i = 0; i < 4; ++i) {
            float v = sfr[0][i] + sfr[1][i] + sfr[2][i] + sfr[3][i];
            v += __shfl_xor(v, 1); v += __shfl_xor(v, 2);
            v += __shfl_xor(v, 4); v += __shfl_xor(v, 8);
            lreg[i] = lreg[i] * ps[i] + v;
        }
#pragma unroll
        for (int f8 = 0; f8 < 8; ++f8)
#pragma unroll
            for (int i = 0; i < 4; ++i)
                octx[f8][i] *= ps[i];

        short* pw = &Ps[wid][0];
#pragma unroll
        for (int f = 0; f < 4; ++f)
#pragma unroll
            for (int i = 0; i < 4; ++i)
                pw[(hi * 4 + i) * SP + f * 16 + lo] = f2bf(sfr[f][i]);
        asm volatile("s_waitcnt lgkmcnt(0)" ::: "memory");
        __builtin_amdgcn_sched_barrier(0);

#pragma unroll
        for (int ks = 0; ks < 2; ++ks) {
            union { bf16x8 v; uint2 u[2]; } pa;
            pa.u[0] = *reinterpret_cast<const uint2*>(pw + lo * SP + ks * 32 + hi * 4);
            pa.u[1] = *reinterpret_cast<const uint2*>(pw + lo * SP + ks * 32 + 16 + hi * 4);
            __builtin_amdgcn_s_setprio(1);
#pragma unroll
            for (int f8 = 0; f8 < 8; ++f8) {
                int d = f8 * 16 + lo;
                int sw2 = ((d >> 3) & 15) << 2;
                const short* vrow = &VsT[d * SV];
                union { bf16x8 v; uint2 u[2]; } vb;
                vb.u[0] = *reinterpret_cast<const uint2*>(vrow + ((ks * 32 + hi * 4) ^ sw2));
                vb.u[1] = *reinterpret_cast<const uint2*>(vrow + ((ks * 32 + 16 + hi * 4) ^ sw2));
                octx[f8] = MFMA32(pa.v, vb.v, octx[f8]);
            }
            __builtin_amdgcn_s_setprio(0);
        }
    }
#undef STAGE_K
#undef LOAD_V

#pragma unroll
    for (int i = 0; i < 4; ++i) {
        float inv = 1.f / lreg[i];
        size_t rb = (size_t)(b * T_ + t0 + hi * 4 + i) * D_ + h * DH_;
#pragma unroll
        for (int f8 = 0; f8 < 8; ++f8)
            ctx[rb + f8 * 16 + lo] = __float2bfloat16(octx[f8][i] * inv);
    }
}

// ---------------------------------------------------------------------------
extern "C" void kernel_launch(void* const* d_in, const int* in_sizes, int n_in,
                              void* d_out, int out_size, void* d_ws, size_t ws_size,
                              hipStream_t stream)
{
    (void)in_sizes; (void)n_in; (void)out_size; (void)ws_size;
    const float* x   = (const float*)d_in[0];
    const float* lns = (const float*)d_in[1];
    const float* lno = (const float*)d_in[2];
    const float* wq  = (const float*)d_in[3];
    const float* wk  = (const float*)d_in[4];
    const float* wv  = (const float*)d_in[5];
    const float* wo  = (const float*)d_in[6];
    const float* w1  = (const float*)d_in[7];
    const float* b1  = (const float*)d_in[8];
    const float* w2  = (const float*)d_in[9];
    const float* b2  = (const float*)d_in[10];
    float* out = (float*)d_out;

    char* ws = (char*)d_ws;
    __hip_bfloat16* wqkvT = (__hip_bfloat16*)(ws);                 // 6144x2048 bf16
    __hip_bfloat16* woT   = (__hip_bfloat16*)(ws + 25165824);      // 2048x2048
    __hip_bfloat16* w1T   = (__hip_bfloat16*)(ws + 33554432);      // 8192x2048
    __hip_bfloat16* w2T   = (__hip_bfloat16*)(ws + 67108864);      // 2048x8192
    __hip_bfloat16* xn    = (__hip_bfloat16*)(ws + 100663296);     // 4096x2048 (xn / xn2)
    __hip_bfloat16* qkv   = (__hip_bfloat16*)(ws + 117440512);     // 4096x6144
    __hip_bfloat16* hbuf  = qkv;                                   // 4096x8192 (aliases qkv+ctx)
    __hip_bfloat16* ctx   = (__hip_bfloat16*)(ws + 167772160);     // 4096x2048
    float*          x1    = (float*)(ws + 184549376);              // 4096x2048 f32

    transpose_cvt<<<dim3(32, 64),  256, 0, stream>>>(wq, wqkvT, 2048, 2048, 2048, 0);
    transpose_cvt<<<dim3(32, 64),  256, 0, stream>>>(wk, wqkvT, 2048, 2048, 2048, 2048);
    transpose_cvt<<<dim3(32, 64),  256, 0, stream>>>(wv, wqkvT, 2048, 2048, 2048, 4096);
    transpose_cvt<<<dim3(32, 64),  256, 0, stream>>>(wo, woT,   2048, 2048, 2048, 0);
    transpose_cvt<<<dim3(128, 64), 256, 0, stream>>>(w1, w1T,   2048, 8192, 2048, 0);
    transpose_cvt<<<dim3(32, 256), 256, 0, stream>>>(w2, w2T,   8192, 2048, 8192, 0);

    ln_kernel<<<4096, 256, 0, stream>>>(x, lns, lno, xn);
    gemmW<0, 128><<<dim3(24, 32), 256, 0, stream>>>(xn, wqkvT, qkv, nullptr, nullptr, 4096, 6144, 2048);
    rope_kernel<<<8192, 256, 0, stream>>>(qkv);
    attn_kernel<<<dim3(32, 32), 256, 0, stream>>>(qkv, ctx);
    gemmW<1, 128><<<dim3(8, 32), 256, 0, stream>>>(ctx, woT, x1, nullptr, x, 4096, 2048, 2048);
    ln_kernel<<<4096, 256, 0, stream>>>(x1, lns, lno, xn);
    gemmW<2, 256><<<dim3(32, 16), 256, 0, stream>>>(xn, w1T, hbuf, b1, nullptr, 4096, 8192, 2048);
    gemmW<3, 128><<<dim3(8, 32), 256, 0, stream>>>(hbuf, w2T, out, b2, x1, 4096, 2048, 8192);
}

// Round 7
// 846.372 us; speedup vs baseline: 1.1615x; 1.1615x over previous
//
#include <hip/hip_runtime.h>
#include <hip/hip_bf16.h>

#define B_   2
#define T_   2048
#define D_   2048
#define H_   16
#define DH_  128
#define DFF_ 8192

typedef __attribute__((ext_vector_type(8))) short bf16x8;
typedef __attribute__((ext_vector_type(4))) float f32x4;

__device__ __forceinline__ short f2bf(float f) {
    __hip_bfloat16 h = __float2bfloat16(f);
    return *reinterpret_cast<short*>(&h);
}

__device__ __forceinline__ void gload_lds16(const void* g, void* l) {
    __builtin_amdgcn_global_load_lds(
        (const __attribute__((address_space(1))) void*)g,
        (__attribute__((address_space(3))) void*)l,
        16, 0, 0);
}

__device__ __forceinline__ float gelu_tanh(float x) {
    float x3 = x * x * x;
    return 0.5f * x * (1.f + tanhf(0.7978845608028654f * (x + 0.044715f * x3)));
}

#define MFMA32(a, b, c) __builtin_amdgcn_mfma_f32_16x16x32_bf16((a), (b), (c), 0, 0, 0)

// ---------------------------------------------------------------------------
// Transpose + f32->bf16 convert (unchanged)
// ---------------------------------------------------------------------------
__global__ __launch_bounds__(256) void transpose_cvt(const float* __restrict__ in,
                                                     __hip_bfloat16* __restrict__ out,
                                                     int K, int N, int out_ld, int out_row0)
{
    __shared__ float t[32][65];
    const int n0 = blockIdx.x * 64, k0 = blockIdx.y * 32;
    const int tid = threadIdx.x;
    {
        int kr = tid >> 4;
        int nc = (tid & 15) * 4;
        const float* src = in + (size_t)(k0 + kr) * N + n0 + nc;
        float4 a = *reinterpret_cast<const float4*>(src);
        float4 b = *reinterpret_cast<const float4*>(src + (size_t)16 * N);
        t[kr][nc] = a.x; t[kr][nc + 1] = a.y; t[kr][nc + 2] = a.z; t[kr][nc + 3] = a.w;
        t[kr + 16][nc] = b.x; t[kr + 16][nc + 1] = b.y; t[kr + 16][nc + 2] = b.z; t[kr + 16][nc + 3] = b.w;
    }
    __syncthreads();
    {
        int n  = tid >> 2;
        int kc = (tid & 3) * 8;
        __hip_bfloat16 ob[8];
#pragma unroll
        for (int j = 0; j < 8; ++j) ob[j] = __float2bfloat16(t[kc + j][n]);
        *reinterpret_cast<uint4*>(out + (size_t)(out_row0 + n0 + n) * out_ld + k0 + kc) =
            *reinterpret_cast<uint4*>(ob);
    }
}

// ---------------------------------------------------------------------------
// LayerNorm (unchanged)
// ---------------------------------------------------------------------------
__global__ __launch_bounds__(256) void ln_kernel(const float* __restrict__ x,
                                                 const float* __restrict__ sc,
                                                 const float* __restrict__ of,
                                                 __hip_bfloat16* __restrict__ out)
{
    int row = blockIdx.x, tid = threadIdx.x;
    const float* xr = x + (size_t)row * D_;
    float4 v0 = reinterpret_cast<const float4*>(xr)[tid * 2];
    float4 v1 = reinterpret_cast<const float4*>(xr)[tid * 2 + 1];
    float vv[8] = {v0.x, v0.y, v0.z, v0.w, v1.x, v1.y, v1.z, v1.w};
    float s = 0.f, ss = 0.f;
#pragma unroll
    for (int j = 0; j < 8; ++j) { s += vv[j]; ss += vv[j] * vv[j]; }
    for (int o = 32; o; o >>= 1) { s += __shfl_down(s, o); ss += __shfl_down(ss, o); }
    __shared__ float red[8];
    int wid = tid >> 6, lane = tid & 63;
    if (!lane) { red[wid] = s; red[4 + wid] = ss; }
    __syncthreads();
    s  = red[0] + red[1] + red[2] + red[3];
    ss = red[4] + red[5] + red[6] + red[7];
    float mean = s * (1.f / D_);
    float var  = ss * (1.f / D_) - mean * mean;
    float rstd = rsqrtf(var + 1e-5f);
    int c0 = tid * 8;
    __hip_bfloat16 ob[8];
#pragma unroll
    for (int j = 0; j < 8; ++j)
        ob[j] = __float2bfloat16((vv[j] - mean) * rstd * sc[c0 + j] + of[c0 + j]);
    *reinterpret_cast<uint4*>(out + (size_t)row * D_ + c0) = *reinterpret_cast<uint4*>(ob);
}

// ---------------------------------------------------------------------------
// 8-phase counted-vmcnt GEMM, r5 structure with 4-phase-cover staging.
// Tile BM x 256, BK=64 as 2 k-slices. 512 thr = 8 waves (2M x 4N); per-wave
// BM/2 x 64, acc[MFR][4].
// NEW (r7): both ks0 units (A+B) issued at P0, both ks1 units at P1.
//   P1-end vmcnt(2*(LA+2)) guards tile-t ks1   (issued t-1.P1, 4-phase cover)
//   P3-end vmcnt(LA+2)     guards tile-t+1 ks0 (issued t.P0,   4-phase cover)
// -> every staged unit has >=4 phases (~1000cy) of latency cover vs ~500cy
// in r5; queue never drains mid-loop.
// EPI: 0 bf16 out; 1 f32+resid; 2 bf16+bias+gelu; 3 f32+bias+resid
// ---------------------------------------------------------------------------
template<int EPI, int BM>
__global__ __launch_bounds__(512, 2) void gemm8p(
    const __hip_bfloat16* __restrict__ A, const __hip_bfloat16* __restrict__ BT,
    void* __restrict__ Cout, const float* __restrict__ bias,
    const float* __restrict__ resid, int M, int N, int K)
{
    constexpr int MFR = BM / 32;        // m-frags per wave (8 or 4)
    constexpr int LA  = BM / 128;       // A-unit loads per thread (2 or 1)
    constexpr int VM1 = 2 * (LA + 2);   // P1-end: leave both t+1 ks-groups
    constexpr int VM3 = LA + 2;         // P3-end: leave t+1 ks1 group
    __shared__ short As[2 * 2 * BM * 32];
    __shared__ short Bs[2 * 2 * 256 * 32];

    const int tid = threadIdx.x;
    const int wid = tid >> 6, lane = tid & 63;
    const int lo = lane & 15, hi = lane >> 4;
    const int wr = wid >> 2, wc = wid & 3;

    // bijective XCD swizzle (all grids have nwg % 8 == 0)
    const int gx = gridDim.x;
    const int nwg = gx * gridDim.y;
    const int bid = blockIdx.y * gx + blockIdx.x;
    const int swz = (bid & 7) * (nwg >> 3) + (bid >> 3);
    const int m0 = (swz / gx) * BM, n0 = (swz % gx) * 256;

    auto stageA = [&](int tt, int ks) {
#pragma unroll
        for (int l = 0; l < LA; ++l) {
            int c    = l * 512 + tid;
            int row  = c >> 2, ksub = c & 3;
            int kc   = tt * 64 + ks * 32 + ((ksub ^ ((row >> 1) & 3)) << 3);
            int c0   = l * 512 + wid * 64;                  // wave-uniform
            gload_lds16(A + (size_t)(m0 + row) * K + kc,
                        (char*)As + ((tt & 1) * 2 + ks) * (BM * 64) + c0 * 16);
        }
    };
    auto stageB = [&](int tt, int ks) {
#pragma unroll
        for (int l = 0; l < 2; ++l) {
            int c    = l * 512 + tid;
            int row  = c >> 2, ksub = c & 3;
            int kc   = tt * 64 + ks * 32 + ((ksub ^ ((row >> 1) & 3)) << 3);
            int c0   = l * 512 + wid * 64;
            gload_lds16(BT + (size_t)(n0 + row) * K + kc,
                        (char*)Bs + ((tt & 1) * 2 + ks) * 16384 + c0 * 16);
        }
    };

    const int fsw  = (hi ^ ((lo >> 1) & 3)) << 4;   // frag slot (bytes)
    const int arow = wr * (BM / 2) + lo;
    const int brow = wc * 64 + lo;

    f32x4 acc[MFR][4] = {};
    const int NT = K >> 6;

    // prologue: 4 units of tile 0, full drain (one-time cost)
    stageA(0, 0); stageB(0, 0); stageA(0, 1); stageB(0, 1);
    asm volatile("s_waitcnt vmcnt(0)" ::: "memory");
    __builtin_amdgcn_s_barrier();
    __builtin_amdgcn_sched_barrier(0);

#define PHASE_MFMA(J)                                                         \
        __builtin_amdgcn_s_barrier();                                         \
        asm volatile("s_waitcnt lgkmcnt(0)" ::: "memory");                    \
        __builtin_amdgcn_sched_barrier(0);                                    \
        __builtin_amdgcn_s_setprio(1);                                        \
        _Pragma("unroll")                                                     \
        for (int m = 0; m < MFR; ++m) {                                       \
            acc[m][J]     = MFMA32(af[m], b0, acc[m][J]);                     \
            acc[m][J + 1] = MFMA32(af[m], b1, acc[m][J + 1]);                 \
        }                                                                     \
        __builtin_amdgcn_s_setprio(0);

#pragma unroll 2
    for (int t = 0; t < NT; ++t) {
        const int bsel = t & 1;
        const bool pf = (t + 1 < NT);
        const char* Ab = (const char*)As + bsel * (2 * BM * 64);
        const char* Bb = (const char*)Bs + bsel * 32768;
        bf16x8 af[MFR], b0, b1;

        // ---- P0: (ks0, nh0); issue BOTH ks0 units of tile t+1
#pragma unroll
        for (int m = 0; m < MFR; ++m)
            af[m] = *reinterpret_cast<const bf16x8*>(Ab + (arow + m * 16) * 64 + fsw);
        b0 = *reinterpret_cast<const bf16x8*>(Bb + brow * 64 + fsw);
        b1 = *reinterpret_cast<const bf16x8*>(Bb + (brow + 16) * 64 + fsw);
        if (pf) { stageA(t + 1, 0); stageB(t + 1, 0); }
        PHASE_MFMA(0)
        __builtin_amdgcn_s_barrier();
        __builtin_amdgcn_sched_barrier(0);

        // ---- P1: (ks0, nh1) — af reused; issue BOTH ks1 units of tile t+1
        b0 = *reinterpret_cast<const bf16x8*>(Bb + (brow + 32) * 64 + fsw);
        b1 = *reinterpret_cast<const bf16x8*>(Bb + (brow + 48) * 64 + fsw);
        if (pf) { stageA(t + 1, 1); stageB(t + 1, 1); }
        PHASE_MFMA(2)
        // guard tile-t ks1 (issued t-1.P1 -> 4-phase cover); keep t+1 in flight
        if (pf) asm volatile("s_waitcnt vmcnt(%0)" :: "i"(VM1) : "memory");
        else    asm volatile("s_waitcnt vmcnt(0)" ::: "memory");
        __builtin_amdgcn_s_barrier();
        __builtin_amdgcn_sched_barrier(0);

        // ---- P2: (ks1, nh0)
#pragma unroll
        for (int m = 0; m < MFR; ++m)
            af[m] = *reinterpret_cast<const bf16x8*>(Ab + BM * 64 + (arow + m * 16) * 64 + fsw);
        b0 = *reinterpret_cast<const bf16x8*>(Bb + 16384 + brow * 64 + fsw);
        b1 = *reinterpret_cast<const bf16x8*>(Bb + 16384 + (brow + 16) * 64 + fsw);
        PHASE_MFMA(0)
        __builtin_amdgcn_s_barrier();
        __builtin_amdgcn_sched_barrier(0);

        // ---- P3: (ks1, nh1)
        b0 = *reinterpret_cast<const bf16x8*>(Bb + 16384 + (brow + 32) * 64 + fsw);
        b1 = *reinterpret_cast<const bf16x8*>(Bb + 16384 + (brow + 48) * 64 + fsw);
        PHASE_MFMA(2)
        // guard tile-t+1 ks0 (issued t.P0 -> 4-phase cover); leave t+1 ks1
        if (pf) asm volatile("s_waitcnt vmcnt(%0)" :: "i"(VM3) : "memory");
        else    asm volatile("s_waitcnt vmcnt(0)" ::: "memory");
        __builtin_amdgcn_s_barrier();
        __builtin_amdgcn_sched_barrier(0);
    }
#undef PHASE_MFMA

    // ---- epilogue
    float* Cf = (float*)Cout;
    __hip_bfloat16* Cb = (__hip_bfloat16*)Cout;
#pragma unroll
    for (int m = 0; m < MFR; ++m) {
        int rbase = m0 + wr * (BM / 2) + m * 16 + hi * 4;
#pragma unroll
        for (int j = 0; j < 4; ++j) {
            int col = n0 + wc * 64 + (j >> 1) * 32 + (j & 1) * 16 + lo;
            float bv = (EPI == 2 || EPI == 3) ? bias[col] : 0.f;
#pragma unroll
            for (int i = 0; i < 4; ++i) {
                size_t idx = (size_t)(rbase + i) * N + col;
                float v = acc[m][j][i];
                if (EPI == 2 || EPI == 3) v += bv;
                if (EPI == 2) v = gelu_tanh(v);
                if (EPI == 1 || EPI == 3) v += resid[idx];
                if (EPI == 0 || EPI == 2) Cb[idx] = __float2bfloat16(v);
                else                      Cf[idx] = v;
            }
        }
    }
}

// ---------------------------------------------------------------------------
// RoPE (unchanged)
// ---------------------------------------------------------------------------
__global__ __launch_bounds__(256) void rope_kernel(__hip_bfloat16* __restrict__ qkv)
{
    int idx = blockIdx.x * 256 + threadIdx.x;
    int p  = idx & 31;
    int h  = (idx >> 5) & (H_ - 1);
    int bt = idx >> 9;
    int t  = bt & (T_ - 1);
    float invf = exp2f((float)p * -0.4152410118609203f);
    float fr = (float)t * invf;
    float cs, sn;
    __sincosf(fr, &sn, &cs);
    size_t base = (size_t)bt * (3 * D_) + h * DH_ + 2 * p;
#pragma unroll
    for (int qk = 0; qk < 2; ++qk) {
        uint* pp = reinterpret_cast<uint*>(qkv + base + qk * D_);
        uint u = *pp;
        float x1 = __uint_as_float(u << 16);
        float x2 = __uint_as_float(u & 0xffff0000u);
        short r0 = f2bf(x1 * cs - x2 * sn);
        short r1 = f2bf(x2 * cs + x1 * sn);
        *pp = ((uint)(unsigned short)r0) | (((uint)(unsigned short)r1) << 16);
    }
}

// ---------------------------------------------------------------------------
// Causal flash attention (r4/r5 version, unchanged — passed three times)
// ---------------------------------------------------------------------------
__global__ __launch_bounds__(256) void attn_kernel(const __hip_bfloat16* __restrict__ qkv,
                                                   __hip_bfloat16* __restrict__ ctx)
{
    constexpr int LDQ = 3 * D_;
    constexpr int SV  = 68;
    constexpr int SP  = 68;

    int idx = blockIdx.y * 32 + blockIdx.x;
    int swz = (idx & 7) * 128 + (idx >> 3);
    const int bh  = swz >> 5;
    const int bxr = 31 - (swz & 31);
    const int b = bh >> 4, h = bh & 15;
    const int tq0 = bxr * 64;

    const int tid = threadIdx.x, wid = tid >> 6, lane = tid & 63;
    const int lo = lane & 15, hi = lane >> 4;
    const int t0 = tq0 + wid * 16;

    __shared__ short Ks[2][64 * 128];
    __shared__ short VsT[128 * SV];
    __shared__ short Ps[4][16 * SP];

    const __hip_bfloat16* qrow = qkv + (size_t)(b * T_ + t0 + lo) * LDQ + h * DH_;
    bf16x8 qf[4];
#pragma unroll
    for (int dk = 0; dk < 4; ++dk)
        qf[dk] = *reinterpret_cast<const bf16x8*>(qrow + dk * 32 + hi * 8);

    f32x4 octx[8] = {};
    float mreg[4] = {-1e30f, -1e30f, -1e30f, -1e30f};
    float lreg[4] = {0.f, 0.f, 0.f, 0.f};

    const size_t kvrow0 = (size_t)(b * T_) * LDQ + h * DH_;
    const int nst = bxr + 1;

    const int kc = wid * 256 + lane;
    bf16x8 vr[4];

#define STAGE_K(s0v, buf)                                                     \
    do {                                                                      \
        _Pragma("unroll")                                                     \
        for (int i = 0; i < 4; ++i) {                                         \
            int c    = kc + i * 64;                                           \
            int sr   = c >> 4;                                                \
            int cbs  = ((c & 15) * 16) ^ ((sr & 7) << 4);                     \
            gload_lds16(qkv + kvrow0 + (size_t)((s0v) + sr) * LDQ + D_ + (cbs >> 1), \
                        &Ks[buf][(kc + i * 64) * 8]);                         \
        }                                                                     \
    } while (0)

#define LOAD_V(s0v)                                                           \
    do {                                                                      \
        _Pragma("unroll")                                                     \
        for (int it = 0; it < 4; ++it) {                                      \
            int c = it * 256 + tid;                                           \
            int s = c >> 4, dc = c & 15;                                      \
            vr[it] = *reinterpret_cast<const bf16x8*>(                        \
                qkv + kvrow0 + (size_t)((s0v) + s) * LDQ + 2 * D_ + dc * 8);  \
        }                                                                     \
    } while (0)

    STAGE_K(0, 0);
    LOAD_V(0);

    for (int st = 0; st < nst; ++st) {
        const int s0 = st * 64;
        const int cur = st & 1;
        __syncthreads();

#pragma unroll
        for (int it = 0; it < 4; ++it) {
            int c = it * 256 + tid;
            int s = c >> 4, dc = c & 15;
            int sswz = s ^ ((dc & 15) << 2);
            short* dst = &VsT[(dc * 8) * SV + sswz];
#pragma unroll
            for (int j = 0; j < 8; ++j)
                dst[j * SV] = vr[it][j];
        }
        if (st + 1 < nst) {
            STAGE_K(s0 + 64, cur ^ 1);
            LOAD_V(s0 + 64);
        }
        asm volatile("s_waitcnt lgkmcnt(0)" ::: "memory");
        __builtin_amdgcn_s_barrier();
        __builtin_amdgcn_sched_barrier(0);

        f32x4 sfr[4] = {};
        __builtin_amdgcn_s_setprio(1);
#pragma unroll
        for (int f = 0; f < 4; ++f) {
            int srow = f * 16 + lo;
            int sw = (srow & 7) << 4;
#pragma unroll
            for (int dk = 0; dk < 4; ++dk) {
                bf16x8 kf = *reinterpret_cast<const bf16x8*>(
                    (const char*)&Ks[cur][0] + srow * 256 + ((dk * 64 + hi * 16) ^ sw));
                sfr[f] = MFMA32(qf[dk], kf, sfr[f]);
            }
        }
        __builtin_amdgcn_s_setprio(0);

        const float qsc = 0.08838834764831845f;
#pragma unroll
        for (int f = 0; f < 4; ++f)
#pragma unroll
            for (int i = 0; i < 4; ++i)
                sfr[f][i] *= qsc;
        if (st == nst - 1) {
#pragma unroll
            for (int f = 0; f < 4; ++f)
#pragma unroll
                for (int i = 0; i < 4; ++i)
                    if (s0 + f * 16 + lo > t0 + hi * 4 + i) sfr[f][i] = -1e30f;
        }

        float ps[4];
#pragma unroll
        for (int i = 0; i < 4; ++i) {
            float v = fmaxf(fmaxf(sfr[0][i], sfr[1][i]), fmaxf(sfr[2][i], sfr[3][i]));
            v = fmaxf(v, __shfl_xor(v, 1));
            v = fmaxf(v, __shfl_xor(v, 2));
            v = fmaxf(v, __shfl_xor(v, 4));
            v = fmaxf(v, __shfl_xor(v, 8));
            float mn = fmaxf(mreg[i], v);
            ps[i] = __expf(mreg[i] - mn);
            mreg[i] = mn;
        }
#pragma unroll
        for (int f = 0; f < 4; ++f)
#pragma unroll
            for (int i = 0; i < 4; ++i)
                sfr[f][i] = __expf(sfr[f][i] - mreg[i]);
#pragma unroll
        for (int i = 0; i < 4; ++i) {
            float v = sfr[0][i] + sfr[1][i] + sfr[2][i] + sfr[3][i];
            v += __shfl_xor(v, 1); v += __shfl_xor(v, 2);
            v += __shfl_xor(v, 4); v += __shfl_xor(v, 8);
            lreg[i] = lreg[i] * ps[i] + v;
        }
#pragma unroll
        for (int f8 = 0; f8 < 8; ++f8)
#pragma unroll
            for (int i = 0; i < 4; ++i)
                octx[f8][i] *= ps[i];

        short* pw = &Ps[wid][0];
#pragma unroll
        for (int f = 0; f < 4; ++f)
#pragma unroll
            for (int i = 0; i < 4; ++i)
                pw[(hi * 4 + i) * SP + f * 16 + lo] = f2bf(sfr[f][i]);
        asm volatile("s_waitcnt lgkmcnt(0)" ::: "memory");
        __builtin_amdgcn_sched_barrier(0);

#pragma unroll
        for (int ks = 0; ks < 2; ++ks) {
            union { bf16x8 v; uint2 u[2]; } pa;
            pa.u[0] = *reinterpret_cast<const uint2*>(pw + lo * SP + ks * 32 + hi * 4);
            pa.u[1] = *reinterpret_cast<const uint2*>(pw + lo * SP + ks * 32 + 16 + hi * 4);
            __builtin_amdgcn_s_setprio(1);
#pragma unroll
            for (int f8 = 0; f8 < 8; ++f8) {
                int d = f8 * 16 + lo;
                int sw2 = ((d >> 3) & 15) << 2;
                const short* vrow = &VsT[d * SV];
                union { bf16x8 v; uint2 u[2]; } vb;
                vb.u[0] = *reinterpret_cast<const uint2*>(vrow + ((ks * 32 + hi * 4) ^ sw2));
                vb.u[1] = *reinterpret_cast<const uint2*>(vrow + ((ks * 32 + 16 + hi * 4) ^ sw2));
                octx[f8] = MFMA32(pa.v, vb.v, octx[f8]);
            }
            __builtin_amdgcn_s_setprio(0);
        }
    }
#undef STAGE_K
#undef LOAD_V

#pragma unroll
    for (int i = 0; i < 4; ++i) {
        float inv = 1.f / lreg[i];
        size_t rb = (size_t)(b * T_ + t0 + hi * 4 + i) * D_ + h * DH_;
#pragma unroll
        for (int f8 = 0; f8 < 8; ++f8)
            ctx[rb + f8 * 16 + lo] = __float2bfloat16(octx[f8][i] * inv);
    }
}

// ---------------------------------------------------------------------------
extern "C" void kernel_launch(void* const* d_in, const int* in_sizes, int n_in,
                              void* d_out, int out_size, void* d_ws, size_t ws_size,
                              hipStream_t stream)
{
    (void)in_sizes; (void)n_in; (void)out_size; (void)ws_size;
    const float* x   = (const float*)d_in[0];
    const float* lns = (const float*)d_in[1];
    const float* lno = (const float*)d_in[2];
    const float* wq  = (const float*)d_in[3];
    const float* wk  = (const float*)d_in[4];
    const float* wv  = (const float*)d_in[5];
    const float* wo  = (const float*)d_in[6];
    const float* w1  = (const float*)d_in[7];
    const float* b1  = (const float*)d_in[8];
    const float* w2  = (const float*)d_in[9];
    const float* b2  = (const float*)d_in[10];
    float* out = (float*)d_out;

    char* ws = (char*)d_ws;
    __hip_bfloat16* wqkvT = (__hip_bfloat16*)(ws);                 // 6144x2048 bf16
    __hip_bfloat16* woT   = (__hip_bfloat16*)(ws + 25165824);      // 2048x2048
    __hip_bfloat16* w1T   = (__hip_bfloat16*)(ws + 33554432);      // 8192x2048
    __hip_bfloat16* w2T   = (__hip_bfloat16*)(ws + 67108864);      // 2048x8192
    __hip_bfloat16* xn    = (__hip_bfloat16*)(ws + 100663296);     // 4096x2048 (xn / xn2)
    __hip_bfloat16* qkv   = (__hip_bfloat16*)(ws + 117440512);     // 4096x6144
    __hip_bfloat16* hbuf  = qkv;                                   // 4096x8192 (aliases qkv+ctx)
    __hip_bfloat16* ctx   = (__hip_bfloat16*)(ws + 167772160);     // 4096x2048
    float*          x1    = (float*)(ws + 184549376);              // 4096x2048 f32

    transpose_cvt<<<dim3(32, 64),  256, 0, stream>>>(wq, wqkvT, 2048, 2048, 2048, 0);
    transpose_cvt<<<dim3(32, 64),  256, 0, stream>>>(wk, wqkvT, 2048, 2048, 2048, 2048);
    transpose_cvt<<<dim3(32, 64),  256, 0, stream>>>(wv, wqkvT, 2048, 2048, 2048, 4096);
    transpose_cvt<<<dim3(32, 64),  256, 0, stream>>>(wo, woT,   2048, 2048, 2048, 0);
    transpose_cvt<<<dim3(128, 64), 256, 0, stream>>>(w1, w1T,   2048, 8192, 2048, 0);
    transpose_cvt<<<dim3(32, 256), 256, 0, stream>>>(w2, w2T,   8192, 2048, 8192, 0);

    ln_kernel<<<4096, 256, 0, stream>>>(x, lns, lno, xn);
    gemm8p<0, 128><<<dim3(24, 32), 512, 0, stream>>>(xn, wqkvT, qkv, nullptr, nullptr, 4096, 6144, 2048);
    rope_kernel<<<8192, 256, 0, stream>>>(qkv);
    attn_kernel<<<dim3(32, 32), 256, 0, stream>>>(qkv, ctx);
    gemm8p<1, 128><<<dim3(8, 32), 512, 0, stream>>>(ctx, woT, x1, nullptr, x, 4096, 2048, 2048);
    ln_kernel<<<4096, 256, 0, stream>>>(x1, lns, lno, xn);
    gemm8p<2, 256><<<dim3(32, 16), 512, 0, stream>>>(xn, w1T, hbuf, b1, nullptr, 4096, 8192, 2048);
    gemm8p<3, 128><<<dim3(8, 32), 512, 0, stream>>>(hbuf, w2T, out, b2, x1, 4096, 2048, 8192);
}

// Round 8
// 802.585 us; speedup vs baseline: 1.2248x; 1.0546x over previous
//
#include <hip/hip_runtime.h>
#include <hip/hip_bf16.h>

#define B_   2
#define T_   2048
#define D_   2048
#define H_   16
#define DH_  128
#define DFF_ 8192

typedef __attribute__((ext_vector_type(8))) short bf16x8;
typedef __attribute__((ext_vector_type(4))) float f32x4;

__device__ __forceinline__ short f2bf(float f) {
    __hip_bfloat16 h = __float2bfloat16(f);
    return *reinterpret_cast<short*>(&h);
}

__device__ __forceinline__ void gload_lds16(const void* g, void* l) {
    __builtin_amdgcn_global_load_lds(
        (const __attribute__((address_space(1))) void*)g,
        (__attribute__((address_space(3))) void*)l,
        16, 0, 0);
}

__device__ __forceinline__ float gelu_tanh(float x) {
    float x3 = x * x * x;
    return 0.5f * x * (1.f + tanhf(0.7978845608028654f * (x + 0.044715f * x3)));
}

#define MFMA32(a, b, c) __builtin_amdgcn_mfma_f32_16x16x32_bf16((a), (b), (c), 0, 0, 0)

// ---------------------------------------------------------------------------
// Transpose + f32->bf16 convert (unchanged)
// ---------------------------------------------------------------------------
__global__ __launch_bounds__(256) void transpose_cvt(const float* __restrict__ in,
                                                     __hip_bfloat16* __restrict__ out,
                                                     int K, int N, int out_ld, int out_row0)
{
    __shared__ float t[32][65];
    const int n0 = blockIdx.x * 64, k0 = blockIdx.y * 32;
    const int tid = threadIdx.x;
    {
        int kr = tid >> 4;
        int nc = (tid & 15) * 4;
        const float* src = in + (size_t)(k0 + kr) * N + n0 + nc;
        float4 a = *reinterpret_cast<const float4*>(src);
        float4 b = *reinterpret_cast<const float4*>(src + (size_t)16 * N);
        t[kr][nc] = a.x; t[kr][nc + 1] = a.y; t[kr][nc + 2] = a.z; t[kr][nc + 3] = a.w;
        t[kr + 16][nc] = b.x; t[kr + 16][nc + 1] = b.y; t[kr + 16][nc + 2] = b.z; t[kr + 16][nc + 3] = b.w;
    }
    __syncthreads();
    {
        int n  = tid >> 2;
        int kc = (tid & 3) * 8;
        __hip_bfloat16 ob[8];
#pragma unroll
        for (int j = 0; j < 8; ++j) ob[j] = __float2bfloat16(t[kc + j][n]);
        *reinterpret_cast<uint4*>(out + (size_t)(out_row0 + n0 + n) * out_ld + k0 + kc) =
            *reinterpret_cast<uint4*>(ob);
    }
}

// ---------------------------------------------------------------------------
// LayerNorm (unchanged)
// ---------------------------------------------------------------------------
__global__ __launch_bounds__(256) void ln_kernel(const float* __restrict__ x,
                                                 const float* __restrict__ sc,
                                                 const float* __restrict__ of,
                                                 __hip_bfloat16* __restrict__ out)
{
    int row = blockIdx.x, tid = threadIdx.x;
    const float* xr = x + (size_t)row * D_;
    float4 v0 = reinterpret_cast<const float4*>(xr)[tid * 2];
    float4 v1 = reinterpret_cast<const float4*>(xr)[tid * 2 + 1];
    float vv[8] = {v0.x, v0.y, v0.z, v0.w, v1.x, v1.y, v1.z, v1.w};
    float s = 0.f, ss = 0.f;
#pragma unroll
    for (int j = 0; j < 8; ++j) { s += vv[j]; ss += vv[j] * vv[j]; }
    for (int o = 32; o; o >>= 1) { s += __shfl_down(s, o); ss += __shfl_down(ss, o); }
    __shared__ float red[8];
    int wid = tid >> 6, lane = tid & 63;
    if (!lane) { red[wid] = s; red[4 + wid] = ss; }
    __syncthreads();
    s  = red[0] + red[1] + red[2] + red[3];
    ss = red[4] + red[5] + red[6] + red[7];
    float mean = s * (1.f / D_);
    float var  = ss * (1.f / D_) - mean * mean;
    float rstd = rsqrtf(var + 1e-5f);
    int c0 = tid * 8;
    __hip_bfloat16 ob[8];
#pragma unroll
    for (int j = 0; j < 8; ++j)
        ob[j] = __float2bfloat16((vv[j] - mean) * rstd * sc[c0 + j] + of[c0 + j]);
    *reinterpret_cast<uint4*>(out + (size_t)row * D_ + c0) = *reinterpret_cast<uint4*>(ob);
}

// ---------------------------------------------------------------------------
// 8-phase counted-vmcnt GEMM — EXACT r5 version (best measured: 799 us total).
// Tile BM x 256, BK=64 as 2 k-slices. 512 thr = 8 waves (2M x 4N); per-wave
// BM/2 x 64, acc[MFR][4]. One staging unit per phase, vmcnt(LA+2) at P1/P3.
// EPI: 0 bf16 out; 1 f32+resid; 2 bf16+bias+gelu; 3 f32+bias+resid
// ---------------------------------------------------------------------------
template<int EPI, int BM>
__global__ __launch_bounds__(512, 2) void gemm8p(
    const __hip_bfloat16* __restrict__ A, const __hip_bfloat16* __restrict__ BT,
    void* __restrict__ Cout, const float* __restrict__ bias,
    const float* __restrict__ resid, int M, int N, int K)
{
    constexpr int MFR = BM / 32;        // m-frags per wave (8 or 4)
    constexpr int AUL = BM / 128;       // A-unit loads per thread (2 or 1)
    constexpr int VMC = AUL + 2;        // counted vmcnt (2 newest units)
    __shared__ short As[2 * 2 * BM * 32];
    __shared__ short Bs[2 * 2 * 256 * 32];

    const int tid = threadIdx.x;
    const int wid = tid >> 6, lane = tid & 63;
    const int lo = lane & 15, hi = lane >> 4;
    const int wr = wid >> 2, wc = wid & 3;

    // bijective XCD swizzle (all grids have nwg % 8 == 0)
    const int gx = gridDim.x;
    const int nwg = gx * gridDim.y;
    const int bid = blockIdx.y * gx + blockIdx.x;
    const int swz = (bid & 7) * (nwg >> 3) + (bid >> 3);
    const int m0 = (swz / gx) * BM, n0 = (swz % gx) * 256;

    auto stageA = [&](int tt, int ks) {
#pragma unroll
        for (int l = 0; l < AUL; ++l) {
            int c    = l * 512 + tid;
            int row  = c >> 2, ksub = c & 3;
            int kc   = tt * 64 + ks * 32 + ((ksub ^ ((row >> 1) & 3)) << 3);
            int c0   = l * 512 + wid * 64;                  // wave-uniform
            gload_lds16(A + (size_t)(m0 + row) * K + kc,
                        (char*)As + ((tt & 1) * 2 + ks) * (BM * 64) + c0 * 16);
        }
    };
    auto stageB = [&](int tt, int ks) {
#pragma unroll
        for (int l = 0; l < 2; ++l) {
            int c    = l * 512 + tid;
            int row  = c >> 2, ksub = c & 3;
            int kc   = tt * 64 + ks * 32 + ((ksub ^ ((row >> 1) & 3)) << 3);
            int c0   = l * 512 + wid * 64;
            gload_lds16(BT + (size_t)(n0 + row) * K + kc,
                        (char*)Bs + ((tt & 1) * 2 + ks) * 16384 + c0 * 16);
        }
    };

    const int fsw  = (hi ^ ((lo >> 1) & 3)) << 4;   // frag slot (bytes)
    const int arow = wr * (BM / 2) + lo;
    const int brow = wc * 64 + lo;

    f32x4 acc[MFR][4] = {};
    const int NT = K >> 6;

    // prologue: 4 units of tile 0; leave the 2 newest outstanding
    stageA(0, 0); stageB(0, 0); stageA(0, 1); stageB(0, 1);
    asm volatile("s_waitcnt vmcnt(%0)" :: "i"(VMC) : "memory");
    __builtin_amdgcn_s_barrier();
    __builtin_amdgcn_sched_barrier(0);

#define PHASE_MFMA(J)                                                         \
        __builtin_amdgcn_s_barrier();                                         \
        asm volatile("s_waitcnt lgkmcnt(0)" ::: "memory");                    \
        __builtin_amdgcn_sched_barrier(0);                                    \
        __builtin_amdgcn_s_setprio(1);                                        \
        _Pragma("unroll")                                                     \
        for (int m = 0; m < MFR; ++m) {                                       \
            acc[m][J]     = MFMA32(af[m], b0, acc[m][J]);                     \
            acc[m][J + 1] = MFMA32(af[m], b1, acc[m][J + 1]);                 \
        }                                                                     \
        __builtin_amdgcn_s_setprio(0);

#pragma unroll 2
    for (int t = 0; t < NT; ++t) {
        const int bsel = t & 1;
        const bool pf = (t + 1 < NT);
        const char* Ab = (const char*)As + bsel * (2 * BM * 64);
        const char* Bb = (const char*)Bs + bsel * 32768;
        bf16x8 af[MFR], b0, b1;

        // ---- P0: (ks0, nh0)
#pragma unroll
        for (int m = 0; m < MFR; ++m)
            af[m] = *reinterpret_cast<const bf16x8*>(Ab + (arow + m * 16) * 64 + fsw);
        b0 = *reinterpret_cast<const bf16x8*>(Bb + brow * 64 + fsw);
        b1 = *reinterpret_cast<const bf16x8*>(Bb + (brow + 16) * 64 + fsw);
        if (pf) stageA(t + 1, 0);
        PHASE_MFMA(0)
        __builtin_amdgcn_s_barrier();
        __builtin_amdgcn_sched_barrier(0);

        // ---- P1: (ks0, nh1) — af reused
        b0 = *reinterpret_cast<const bf16x8*>(Bb + (brow + 32) * 64 + fsw);
        b1 = *reinterpret_cast<const bf16x8*>(Bb + (brow + 48) * 64 + fsw);
        if (pf) stageB(t + 1, 0);
        PHASE_MFMA(2)
        asm volatile("s_waitcnt vmcnt(%0)" :: "i"(VMC) : "memory");
        __builtin_amdgcn_s_barrier();
        __builtin_amdgcn_sched_barrier(0);

        // ---- P2: (ks1, nh0)
#pragma unroll
        for (int m = 0; m < MFR; ++m)
            af[m] = *reinterpret_cast<const bf16x8*>(Ab + BM * 64 + (arow + m * 16) * 64 + fsw);
        b0 = *reinterpret_cast<const bf16x8*>(Bb + 16384 + brow * 64 + fsw);
        b1 = *reinterpret_cast<const bf16x8*>(Bb + 16384 + (brow + 16) * 64 + fsw);
        if (pf) stageA(t + 1, 1);
        PHASE_MFMA(0)
        __builtin_amdgcn_s_barrier();
        __builtin_amdgcn_sched_barrier(0);

        // ---- P3: (ks1, nh1)
        b0 = *reinterpret_cast<const bf16x8*>(Bb + 16384 + (brow + 32) * 64 + fsw);
        b1 = *reinterpret_cast<const bf16x8*>(Bb + 16384 + (brow + 48) * 64 + fsw);
        if (pf) stageB(t + 1, 1);
        PHASE_MFMA(2)
        asm volatile("s_waitcnt vmcnt(%0)" :: "i"(VMC) : "memory");
        __builtin_amdgcn_s_barrier();
        __builtin_amdgcn_sched_barrier(0);
    }
#undef PHASE_MFMA

    // ---- epilogue
    float* Cf = (float*)Cout;
    __hip_bfloat16* Cb = (__hip_bfloat16*)Cout;
#pragma unroll
    for (int m = 0; m < MFR; ++m) {
        int rbase = m0 + wr * (BM / 2) + m * 16 + hi * 4;
#pragma unroll
        for (int j = 0; j < 4; ++j) {
            int col = n0 + wc * 64 + (j >> 1) * 32 + (j & 1) * 16 + lo;
            float bv = (EPI == 2 || EPI == 3) ? bias[col] : 0.f;
#pragma unroll
            for (int i = 0; i < 4; ++i) {
                size_t idx = (size_t)(rbase + i) * N + col;
                float v = acc[m][j][i];
                if (EPI == 2 || EPI == 3) v += bv;
                if (EPI == 2) v = gelu_tanh(v);
                if (EPI == 1 || EPI == 3) v += resid[idx];
                if (EPI == 0 || EPI == 2) Cb[idx] = __float2bfloat16(v);
                else                      Cf[idx] = v;
            }
        }
    }
}

// ---------------------------------------------------------------------------
// RoPE (unchanged)
// ---------------------------------------------------------------------------
__global__ __launch_bounds__(256) void rope_kernel(__hip_bfloat16* __restrict__ qkv)
{
    int idx = blockIdx.x * 256 + threadIdx.x;
    int p  = idx & 31;
    int h  = (idx >> 5) & (H_ - 1);
    int bt = idx >> 9;
    int t  = bt & (T_ - 1);
    float invf = exp2f((float)p * -0.4152410118609203f);
    float fr = (float)t * invf;
    float cs, sn;
    __sincosf(fr, &sn, &cs);
    size_t base = (size_t)bt * (3 * D_) + h * DH_ + 2 * p;
#pragma unroll
    for (int qk = 0; qk < 2; ++qk) {
        uint* pp = reinterpret_cast<uint*>(qkv + base + qk * D_);
        uint u = *pp;
        float x1 = __uint_as_float(u << 16);
        float x2 = __uint_as_float(u & 0xffff0000u);
        short r0 = f2bf(x1 * cs - x2 * sn);
        short r1 = f2bf(x2 * cs + x1 * sn);
        *pp = ((uint)(unsigned short)r0) | (((uint)(unsigned short)r1) << 16);
    }
}

// ---------------------------------------------------------------------------
// Causal flash attention v4: QBLK=128, 512 threads (8 waves x 16 q-rows),
// KVBLK=64. Per-wave math identical to the 3x-validated v3; staging/scatter
// per thread halves (each KV tile serves 128 q-rows), and 2 blocks/CU x 8
// waves = 16 waves/CU (4/SIMD) doubles TLP to hide the softmax chain.
// ---------------------------------------------------------------------------
__global__ __launch_bounds__(512) void attn_kernel(const __hip_bfloat16* __restrict__ qkv,
                                                   __hip_bfloat16* __restrict__ ctx)
{
    constexpr int LDQ = 3 * D_;
    constexpr int SV  = 68;
    constexpr int SP  = 68;

    // grid (16, 32) = 512 blocks; XCD chunk swizzle: 64 blocks (4 bh) per XCD;
    // reversed bx so biggest causal ranges dispatch first.
    int idx = blockIdx.y * 16 + blockIdx.x;
    int swz = (idx & 7) * 64 + (idx >> 3);
    const int bh  = swz >> 4;
    const int bxr = 15 - (swz & 15);
    const int b = bh >> 4, h = bh & 15;
    const int tq0 = bxr * 128;

    const int tid = threadIdx.x, wid = tid >> 6, lane = tid & 63;
    const int lo = lane & 15, hi = lane >> 4;
    const int t0 = tq0 + wid * 16;

    __shared__ short Ks[2][64 * 128];              // 32 KB
    __shared__ short VsT[128 * SV];                // 17 KB
    __shared__ short Ps[8][16 * SP];               // 17 KB

    const __hip_bfloat16* qrow = qkv + (size_t)(b * T_ + t0 + lo) * LDQ + h * DH_;
    bf16x8 qf[4];
#pragma unroll
    for (int dk = 0; dk < 4; ++dk)
        qf[dk] = *reinterpret_cast<const bf16x8*>(qrow + dk * 32 + hi * 8);

    f32x4 octx[8] = {};
    float mreg[4] = {-1e30f, -1e30f, -1e30f, -1e30f};
    float lreg[4] = {0.f, 0.f, 0.f, 0.f};

    const size_t kvrow0 = (size_t)(b * T_) * LDQ + h * DH_;
    const int nst = 2 * (bxr + 1);

    bf16x8 vr[2];

#define STAGE_K(s0v, buf)                                                     \
    do {                                                                      \
        _Pragma("unroll")                                                     \
        for (int i = 0; i < 2; ++i) {                                         \
            int c    = i * 512 + tid;                                         \
            int sr   = c >> 4;                                                \
            int cbs  = ((c & 15) * 16) ^ ((sr & 7) << 4);                     \
            gload_lds16(qkv + kvrow0 + (size_t)((s0v) + sr) * LDQ + D_ + (cbs >> 1), \
                        &Ks[buf][c * 8]);                                     \
        }                                                                     \
    } while (0)

#define LOAD_V(s0v)                                                           \
    do {                                                                      \
        _Pragma("unroll")                                                     \
        for (int it = 0; it < 2; ++it) {                                      \
            int c = it * 512 + tid;                                           \
            int s = c >> 4, dc = c & 15;                                      \
            vr[it] = *reinterpret_cast<const bf16x8*>(                        \
                qkv + kvrow0 + (size_t)((s0v) + s) * LDQ + 2 * D_ + dc * 8);  \
        }                                                                     \
    } while (0)

    STAGE_K(0, 0);
    LOAD_V(0);

    for (int st = 0; st < nst; ++st) {
        const int s0 = st * 64;
        const int cur = st & 1;
        __syncthreads();   // full drain: K(st) in LDS, vr = V(st); orders VsT overwrite

        // scatter V(st) -> VsT (conflict-free: stride 68 + XOR swizzle)
#pragma unroll
        for (int it = 0; it < 2; ++it) {
            int c = it * 512 + tid;
            int s = c >> 4, dc = c & 15;
            int sswz = s ^ ((dc & 15) << 2);
            short* dst = &VsT[(dc * 8) * SV + sswz];
#pragma unroll
            for (int j = 0; j < 8; ++j)
                dst[j * SV] = vr[it][j];
        }
        // prefetch tile st+1 (stays in flight across the barrier below)
        if (st + 1 < nst) {
            STAGE_K(s0 + 64, cur ^ 1);
            LOAD_V(s0 + 64);
        }
        asm volatile("s_waitcnt lgkmcnt(0)" ::: "memory");
        __builtin_amdgcn_s_barrier();
        __builtin_amdgcn_sched_barrier(0);

        // ---- S = Q K^T
        f32x4 sfr[4] = {};
        __builtin_amdgcn_s_setprio(1);
#pragma unroll
        for (int f = 0; f < 4; ++f) {
            int srow = f * 16 + lo;
            int sw = (srow & 7) << 4;
#pragma unroll
            for (int dk = 0; dk < 4; ++dk) {
                bf16x8 kf = *reinterpret_cast<const bf16x8*>(
                    (const char*)&Ks[cur][0] + srow * 256 + ((dk * 64 + hi * 16) ^ sw));
                sfr[f] = MFMA32(qf[dk], kf, sfr[f]);
            }
        }
        __builtin_amdgcn_s_setprio(0);

        const float qsc = 0.08838834764831845f;
#pragma unroll
        for (int f = 0; f < 4; ++f)
#pragma unroll
            for (int i = 0; i < 4; ++i)
                sfr[f][i] *= qsc;
        // causal mask: only the last two tiles can cross the diagonal for any
        // wave in this 128-row block; fully-masked fragments yield P=0.
        if (st >= nst - 2) {
#pragma unroll
            for (int f = 0; f < 4; ++f)
#pragma unroll
                for (int i = 0; i < 4; ++i)
                    if (s0 + f * 16 + lo > t0 + hi * 4 + i) sfr[f][i] = -1e30f;
        }

        float ps[4];
#pragma unroll
        for (int i = 0; i < 4; ++i) {
            float v = fmaxf(fmaxf(sfr[0][i], sfr[1][i]), fmaxf(sfr[2][i], sfr[3][i]));
            v = fmaxf(v, __shfl_xor(v, 1));
            v = fmaxf(v, __shfl_xor(v, 2));
            v = fmaxf(v, __shfl_xor(v, 4));
            v = fmaxf(v, __shfl_xor(v, 8));
            float mn = fmaxf(mreg[i], v);
            ps[i] = __expf(mreg[i] - mn);
            mreg[i] = mn;
        }
#pragma unroll
        for (int f = 0; f < 4; ++f)
#pragma unroll
            for (int i = 0; i < 4; ++i)
                sfr[f][i] = __expf(sfr[f][i] - mreg[i]);
#pragma unroll
        for (int i = 0; i < 4; ++i) {
            float v = sfr[0][i] + sfr[1][i] + sfr[2][i] + sfr[3][i];
            v += __shfl_xor(v, 1); v += __shfl_xor(v, 2);
            v += __shfl_xor(v, 4); v += __shfl_xor(v, 8);
            lreg[i] = lreg[i] * ps[i] + v;
        }
#pragma unroll
        for (int f8 = 0; f8 < 8; ++f8)
#pragma unroll
            for (int i = 0; i < 4; ++i)
                octx[f8][i] *= ps[i];

        short* pw = &Ps[wid][0];
#pragma unroll
        for (int f = 0; f < 4; ++f)
#pragma unroll
            for (int i = 0; i < 4; ++i)
                pw[(hi * 4 + i) * SP + f * 16 + lo] = f2bf(sfr[f][i]);
        asm volatile("s_waitcnt lgkmcnt(0)" ::: "memory");
        __builtin_amdgcn_sched_barrier(0);

#pragma unroll
        for (int ks = 0; ks < 2; ++ks) {
            union { bf16x8 v; uint2 u[2]; } pa;
            pa.u[0] = *reinterpret_cast<const uint2*>(pw + lo * SP + ks * 32 + hi * 4);
            pa.u[1] = *reinterpret_cast<const uint2*>(pw + lo * SP + ks * 32 + 16 + hi * 4);
            __builtin_amdgcn_s_setprio(1);
#pragma unroll
            for (int f8 = 0; f8 < 8; ++f8) {
                int d = f8 * 16 + lo;
                int sw2 = ((d >> 3) & 15) << 2;
                const short* vrow = &VsT[d * SV];
                union { bf16x8 v; uint2 u[2]; } vb;
                vb.u[0] = *reinterpret_cast<const uint2*>(vrow + ((ks * 32 + hi * 4) ^ sw2));
                vb.u[1] = *reinterpret_cast<const uint2*>(vrow + ((ks * 32 + 16 + hi * 4) ^ sw2));
                octx[f8] = MFMA32(pa.v, vb.v, octx[f8]);
            }
            __builtin_amdgcn_s_setprio(0);
        }
    }
#undef STAGE_K
#undef LOAD_V

#pragma unroll
    for (int i = 0; i < 4; ++i) {
        float inv = 1.f / lreg[i];
        size_t rb = (size_t)(b * T_ + t0 + hi * 4 + i) * D_ + h * DH_;
#pragma unroll
        for (int f8 = 0; f8 < 8; ++f8)
            ctx[rb + f8 * 16 + lo] = __float2bfloat16(octx[f8][i] * inv);
    }
}

// ---------------------------------------------------------------------------
extern "C" void kernel_launch(void* const* d_in, const int* in_sizes, int n_in,
                              void* d_out, int out_size, void* d_ws, size_t ws_size,
                              hipStream_t stream)
{
    (void)in_sizes; (void)n_in; (void)out_size; (void)ws_size;
    const float* x   = (const float*)d_in[0];
    const float* lns = (const float*)d_in[1];
    const float* lno = (const float*)d_in[2];
    const float* wq  = (const float*)d_in[3];
    const float* wk  = (const float*)d_in[4];
    const float* wv  = (const float*)d_in[5];
    const float* wo  = (const float*)d_in[6];
    const float* w1  = (const float*)d_in[7];
    const float* b1  = (const float*)d_in[8];
    const float* w2  = (const float*)d_in[9];
    const float* b2  = (const float*)d_in[10];
    float* out = (float*)d_out;

    char* ws = (char*)d_ws;
    __hip_bfloat16* wqkvT = (__hip_bfloat16*)(ws);                 // 6144x2048 bf16
    __hip_bfloat16* woT   = (__hip_bfloat16*)(ws + 25165824);      // 2048x2048
    __hip_bfloat16* w1T   = (__hip_bfloat16*)(ws + 33554432);      // 8192x2048
    __hip_bfloat16* w2T   = (__hip_bfloat16*)(ws + 67108864);      // 2048x8192
    __hip_bfloat16* xn    = (__hip_bfloat16*)(ws + 100663296);     // 4096x2048 (xn / xn2)
    __hip_bfloat16* qkv   = (__hip_bfloat16*)(ws + 117440512);     // 4096x6144
    __hip_bfloat16* hbuf  = qkv;                                   // 4096x8192 (aliases qkv+ctx)
    __hip_bfloat16* ctx   = (__hip_bfloat16*)(ws + 167772160);     // 4096x2048
    float*          x1    = (float*)(ws + 184549376);              // 4096x2048 f32

    transpose_cvt<<<dim3(32, 64),  256, 0, stream>>>(wq, wqkvT, 2048, 2048, 2048, 0);
    transpose_cvt<<<dim3(32, 64),  256, 0, stream>>>(wk, wqkvT, 2048, 2048, 2048, 2048);
    transpose_cvt<<<dim3(32, 64),  256, 0, stream>>>(wv, wqkvT, 2048, 2048, 2048, 4096);
    transpose_cvt<<<dim3(32, 64),  256, 0, stream>>>(wo, woT,   2048, 2048, 2048, 0);
    transpose_cvt<<<dim3(128, 64), 256, 0, stream>>>(w1, w1T,   2048, 8192, 2048, 0);
    transpose_cvt<<<dim3(32, 256), 256, 0, stream>>>(w2, w2T,   8192, 2048, 8192, 0);

    ln_kernel<<<4096, 256, 0, stream>>>(x, lns, lno, xn);
    gemm8p<0, 128><<<dim3(24, 32), 512, 0, stream>>>(xn, wqkvT, qkv, nullptr, nullptr, 4096, 6144, 2048);
    rope_kernel<<<8192, 256, 0, stream>>>(qkv);
    attn_kernel<<<dim3(16, 32), 512, 0, stream>>>(qkv, ctx);
    gemm8p<1, 128><<<dim3(8, 32), 512, 0, stream>>>(ctx, woT, x1, nullptr, x, 4096, 2048, 2048);
    ln_kernel<<<4096, 256, 0, stream>>>(x1, lns, lno, xn);
    gemm8p<2, 256><<<dim3(32, 16), 512, 0, stream>>>(xn, w1T, hbuf, b1, nullptr, 4096, 8192, 2048);
    gemm8p<3, 128><<<dim3(8, 32), 512, 0, stream>>>(hbuf, w2T, out, b2, x1, 4096, 2048, 8192);
}

// Round 9
// 769.562 us; speedup vs baseline: 1.2774x; 1.0429x over previous
//
#include <hip/hip_runtime.h>
#include <hip/hip_bf16.h>

#define B_   2
#define T_   2048
#define D_   2048
#define H_   16
#define DH_  128
#define DFF_ 8192

typedef __attribute__((ext_vector_type(8))) short bf16x8;
typedef __attribute__((ext_vector_type(4))) float f32x4;

__device__ __forceinline__ short f2bf(float f) {
    __hip_bfloat16 h = __float2bfloat16(f);
    return *reinterpret_cast<short*>(&h);
}

__device__ __forceinline__ void gload_lds16(const void* g, void* l) {
    __builtin_amdgcn_global_load_lds(
        (const __attribute__((address_space(1))) void*)g,
        (__attribute__((address_space(3))) void*)l,
        16, 0, 0);
}

__device__ __forceinline__ float gelu_tanh(float x) {
    float x3 = x * x * x;
    return 0.5f * x * (1.f + tanhf(0.7978845608028654f * (x + 0.044715f * x3)));
}

#define MFMA32(a, b, c) __builtin_amdgcn_mfma_f32_16x16x32_bf16((a), (b), (c), 0, 0, 0)

// ---------------------------------------------------------------------------
// Transpose + f32->bf16 convert (unchanged)
// ---------------------------------------------------------------------------
__global__ __launch_bounds__(256) void transpose_cvt(const float* __restrict__ in,
                                                     __hip_bfloat16* __restrict__ out,
                                                     int K, int N, int out_ld, int out_row0)
{
    __shared__ float t[32][65];
    const int n0 = blockIdx.x * 64, k0 = blockIdx.y * 32;
    const int tid = threadIdx.x;
    {
        int kr = tid >> 4;
        int nc = (tid & 15) * 4;
        const float* src = in + (size_t)(k0 + kr) * N + n0 + nc;
        float4 a = *reinterpret_cast<const float4*>(src);
        float4 b = *reinterpret_cast<const float4*>(src + (size_t)16 * N);
        t[kr][nc] = a.x; t[kr][nc + 1] = a.y; t[kr][nc + 2] = a.z; t[kr][nc + 3] = a.w;
        t[kr + 16][nc] = b.x; t[kr + 16][nc + 1] = b.y; t[kr + 16][nc + 2] = b.z; t[kr + 16][nc + 3] = b.w;
    }
    __syncthreads();
    {
        int n  = tid >> 2;
        int kc = (tid & 3) * 8;
        __hip_bfloat16 ob[8];
#pragma unroll
        for (int j = 0; j < 8; ++j) ob[j] = __float2bfloat16(t[kc + j][n]);
        *reinterpret_cast<uint4*>(out + (size_t)(out_row0 + n0 + n) * out_ld + k0 + kc) =
            *reinterpret_cast<uint4*>(ob);
    }
}

// ---------------------------------------------------------------------------
// LayerNorm (unchanged)
// ---------------------------------------------------------------------------
__global__ __launch_bounds__(256) void ln_kernel(const float* __restrict__ x,
                                                 const float* __restrict__ sc,
                                                 const float* __restrict__ of,
                                                 __hip_bfloat16* __restrict__ out)
{
    int row = blockIdx.x, tid = threadIdx.x;
    const float* xr = x + (size_t)row * D_;
    float4 v0 = reinterpret_cast<const float4*>(xr)[tid * 2];
    float4 v1 = reinterpret_cast<const float4*>(xr)[tid * 2 + 1];
    float vv[8] = {v0.x, v0.y, v0.z, v0.w, v1.x, v1.y, v1.z, v1.w};
    float s = 0.f, ss = 0.f;
#pragma unroll
    for (int j = 0; j < 8; ++j) { s += vv[j]; ss += vv[j] * vv[j]; }
    for (int o = 32; o; o >>= 1) { s += __shfl_down(s, o); ss += __shfl_down(ss, o); }
    __shared__ float red[8];
    int wid = tid >> 6, lane = tid & 63;
    if (!lane) { red[wid] = s; red[4 + wid] = ss; }
    __syncthreads();
    s  = red[0] + red[1] + red[2] + red[3];
    ss = red[4] + red[5] + red[6] + red[7];
    float mean = s * (1.f / D_);
    float var  = ss * (1.f / D_) - mean * mean;
    float rstd = rsqrtf(var + 1e-5f);
    int c0 = tid * 8;
    __hip_bfloat16 ob[8];
#pragma unroll
    for (int j = 0; j < 8; ++j)
        ob[j] = __float2bfloat16((vv[j] - mean) * rstd * sc[c0 + j] + of[c0 + j]);
    *reinterpret_cast<uint4*>(out + (size_t)row * D_ + c0) = *reinterpret_cast<uint4*>(ob);
}

// ---------------------------------------------------------------------------
// 8-phase counted-vmcnt GEMM — EXACT r5/r8 version (frozen).
// ---------------------------------------------------------------------------
template<int EPI, int BM>
__global__ __launch_bounds__(512, 2) void gemm8p(
    const __hip_bfloat16* __restrict__ A, const __hip_bfloat16* __restrict__ BT,
    void* __restrict__ Cout, const float* __restrict__ bias,
    const float* __restrict__ resid, int M, int N, int K)
{
    constexpr int MFR = BM / 32;        // m-frags per wave (8 or 4)
    constexpr int AUL = BM / 128;       // A-unit loads per thread (2 or 1)
    constexpr int VMC = AUL + 2;        // counted vmcnt (2 newest units)
    __shared__ short As[2 * 2 * BM * 32];
    __shared__ short Bs[2 * 2 * 256 * 32];

    const int tid = threadIdx.x;
    const int wid = tid >> 6, lane = tid & 63;
    const int lo = lane & 15, hi = lane >> 4;
    const int wr = wid >> 2, wc = wid & 3;

    const int gx = gridDim.x;
    const int nwg = gx * gridDim.y;
    const int bid = blockIdx.y * gx + blockIdx.x;
    const int swz = (bid & 7) * (nwg >> 3) + (bid >> 3);
    const int m0 = (swz / gx) * BM, n0 = (swz % gx) * 256;

    auto stageA = [&](int tt, int ks) {
#pragma unroll
        for (int l = 0; l < AUL; ++l) {
            int c    = l * 512 + tid;
            int row  = c >> 2, ksub = c & 3;
            int kc   = tt * 64 + ks * 32 + ((ksub ^ ((row >> 1) & 3)) << 3);
            int c0   = l * 512 + wid * 64;                  // wave-uniform
            gload_lds16(A + (size_t)(m0 + row) * K + kc,
                        (char*)As + ((tt & 1) * 2 + ks) * (BM * 64) + c0 * 16);
        }
    };
    auto stageB = [&](int tt, int ks) {
#pragma unroll
        for (int l = 0; l < 2; ++l) {
            int c    = l * 512 + tid;
            int row  = c >> 2, ksub = c & 3;
            int kc   = tt * 64 + ks * 32 + ((ksub ^ ((row >> 1) & 3)) << 3);
            int c0   = l * 512 + wid * 64;
            gload_lds16(BT + (size_t)(n0 + row) * K + kc,
                        (char*)Bs + ((tt & 1) * 2 + ks) * 16384 + c0 * 16);
        }
    };

    const int fsw  = (hi ^ ((lo >> 1) & 3)) << 4;   // frag slot (bytes)
    const int arow = wr * (BM / 2) + lo;
    const int brow = wc * 64 + lo;

    f32x4 acc[MFR][4] = {};
    const int NT = K >> 6;

    stageA(0, 0); stageB(0, 0); stageA(0, 1); stageB(0, 1);
    asm volatile("s_waitcnt vmcnt(%0)" :: "i"(VMC) : "memory");
    __builtin_amdgcn_s_barrier();
    __builtin_amdgcn_sched_barrier(0);

#define PHASE_MFMA(J)                                                         \
        __builtin_amdgcn_s_barrier();                                         \
        asm volatile("s_waitcnt lgkmcnt(0)" ::: "memory");                    \
        __builtin_amdgcn_sched_barrier(0);                                    \
        __builtin_amdgcn_s_setprio(1);                                        \
        _Pragma("unroll")                                                     \
        for (int m = 0; m < MFR; ++m) {                                       \
            acc[m][J]     = MFMA32(af[m], b0, acc[m][J]);                     \
            acc[m][J + 1] = MFMA32(af[m], b1, acc[m][J + 1]);                 \
        }                                                                     \
        __builtin_amdgcn_s_setprio(0);

#pragma unroll 2
    for (int t = 0; t < NT; ++t) {
        const int bsel = t & 1;
        const bool pf = (t + 1 < NT);
        const char* Ab = (const char*)As + bsel * (2 * BM * 64);
        const char* Bb = (const char*)Bs + bsel * 32768;
        bf16x8 af[MFR], b0, b1;

        // ---- P0: (ks0, nh0)
#pragma unroll
        for (int m = 0; m < MFR; ++m)
            af[m] = *reinterpret_cast<const bf16x8*>(Ab + (arow + m * 16) * 64 + fsw);
        b0 = *reinterpret_cast<const bf16x8*>(Bb + brow * 64 + fsw);
        b1 = *reinterpret_cast<const bf16x8*>(Bb + (brow + 16) * 64 + fsw);
        if (pf) stageA(t + 1, 0);
        PHASE_MFMA(0)
        __builtin_amdgcn_s_barrier();
        __builtin_amdgcn_sched_barrier(0);

        // ---- P1: (ks0, nh1) — af reused
        b0 = *reinterpret_cast<const bf16x8*>(Bb + (brow + 32) * 64 + fsw);
        b1 = *reinterpret_cast<const bf16x8*>(Bb + (brow + 48) * 64 + fsw);
        if (pf) stageB(t + 1, 0);
        PHASE_MFMA(2)
        asm volatile("s_waitcnt vmcnt(%0)" :: "i"(VMC) : "memory");
        __builtin_amdgcn_s_barrier();
        __builtin_amdgcn_sched_barrier(0);

        // ---- P2: (ks1, nh0)
#pragma unroll
        for (int m = 0; m < MFR; ++m)
            af[m] = *reinterpret_cast<const bf16x8*>(Ab + BM * 64 + (arow + m * 16) * 64 + fsw);
        b0 = *reinterpret_cast<const bf16x8*>(Bb + 16384 + brow * 64 + fsw);
        b1 = *reinterpret_cast<const bf16x8*>(Bb + 16384 + (brow + 16) * 64 + fsw);
        if (pf) stageA(t + 1, 1);
        PHASE_MFMA(0)
        __builtin_amdgcn_s_barrier();
        __builtin_amdgcn_sched_barrier(0);

        // ---- P3: (ks1, nh1)
        b0 = *reinterpret_cast<const bf16x8*>(Bb + 16384 + (brow + 32) * 64 + fsw);
        b1 = *reinterpret_cast<const bf16x8*>(Bb + 16384 + (brow + 48) * 64 + fsw);
        if (pf) stageB(t + 1, 1);
        PHASE_MFMA(2)
        asm volatile("s_waitcnt vmcnt(%0)" :: "i"(VMC) : "memory");
        __builtin_amdgcn_s_barrier();
        __builtin_amdgcn_sched_barrier(0);
    }
#undef PHASE_MFMA

    float* Cf = (float*)Cout;
    __hip_bfloat16* Cb = (__hip_bfloat16*)Cout;
#pragma unroll
    for (int m = 0; m < MFR; ++m) {
        int rbase = m0 + wr * (BM / 2) + m * 16 + hi * 4;
#pragma unroll
        for (int j = 0; j < 4; ++j) {
            int col = n0 + wc * 64 + (j >> 1) * 32 + (j & 1) * 16 + lo;
            float bv = (EPI == 2 || EPI == 3) ? bias[col] : 0.f;
#pragma unroll
            for (int i = 0; i < 4; ++i) {
                size_t idx = (size_t)(rbase + i) * N + col;
                float v = acc[m][j][i];
                if (EPI == 2 || EPI == 3) v += bv;
                if (EPI == 2) v = gelu_tanh(v);
                if (EPI == 1 || EPI == 3) v += resid[idx];
                if (EPI == 0 || EPI == 2) Cb[idx] = __float2bfloat16(v);
                else                      Cf[idx] = v;
            }
        }
    }
}

// ---------------------------------------------------------------------------
// RoPE (unchanged)
// ---------------------------------------------------------------------------
__global__ __launch_bounds__(256) void rope_kernel(__hip_bfloat16* __restrict__ qkv)
{
    int idx = blockIdx.x * 256 + threadIdx.x;
    int p  = idx & 31;
    int h  = (idx >> 5) & (H_ - 1);
    int bt = idx >> 9;
    int t  = bt & (T_ - 1);
    float invf = exp2f((float)p * -0.4152410118609203f);
    float fr = (float)t * invf;
    float cs, sn;
    __sincosf(fr, &sn, &cs);
    size_t base = (size_t)bt * (3 * D_) + h * DH_ + 2 * p;
#pragma unroll
    for (int qk = 0; qk < 2; ++qk) {
        uint* pp = reinterpret_cast<uint*>(qkv + base + qk * D_);
        uint u = *pp;
        float x1 = __uint_as_float(u << 16);
        float x2 = __uint_as_float(u & 0xffff0000u);
        short r0 = f2bf(x1 * cs - x2 * sn);
        short r1 = f2bf(x2 * cs + x1 * sn);
        *pp = ((uint)(unsigned short)r0) | (((uint)(unsigned short)r1) << 16);
    }
}

// ---------------------------------------------------------------------------
// Causal flash attention v5: swapped-QK in-register softmax.
// QBLK=128, 512 threads (8 waves x 16 q-rows), KVBLK=64, K double-buffered,
// V scatter to VsT (unchanged). NEW: S^T = mfma(K,Q) so lane holds
// S[kv=16f+4hi+i][q=lo]; softmax reduce = 16 local + shfl_xor(16,32);
// P -> PV A-fragment is a pure in-register cvt (sigma layout match) — the
// P LDS roundtrip (Ps buffer, 16 ds_write + 4 ds_read + lgkmcnt) is gone.
// ps/lreg redistributed to PV-output layout (q=hi*4+i) via 4+4 shfls.
// ---------------------------------------------------------------------------
__global__ __launch_bounds__(512) void attn_kernel(const __hip_bfloat16* __restrict__ qkv,
                                                   __hip_bfloat16* __restrict__ ctx)
{
    constexpr int LDQ = 3 * D_;
    constexpr int SV  = 68;

    // grid (16, 32) = 512 blocks; XCD chunk swizzle; reversed bx for balance.
    int idx = blockIdx.y * 16 + blockIdx.x;
    int swz = (idx & 7) * 64 + (idx >> 3);
    const int bh  = swz >> 4;
    const int bxr = 15 - (swz & 15);
    const int b = bh >> 4, h = bh & 15;
    const int tq0 = bxr * 128;

    const int tid = threadIdx.x, wid = tid >> 6, lane = tid & 63;
    const int lo = lane & 15, hi = lane >> 4;
    const int t0 = tq0 + wid * 16;

    __shared__ short Ks[2][64 * 128];              // 32 KB
    __shared__ short VsT[128 * SV];                // 17 KB

    // Q fragment (B-operand layout): q row = t0+lo, k = dk*32 + hi*8
    const __hip_bfloat16* qrow = qkv + (size_t)(b * T_ + t0 + lo) * LDQ + h * DH_;
    bf16x8 qf[4];
#pragma unroll
    for (int dk = 0; dk < 4; ++dk)
        qf[dk] = *reinterpret_cast<const bf16x8*>(qrow + dk * 32 + hi * 8);

    f32x4 octx[8] = {};
    float mreg = -1e30f, lreg = 0.f;

    const size_t kvrow0 = (size_t)(b * T_) * LDQ + h * DH_;
    const int nst = 2 * (bxr + 1);

    bf16x8 vr[2];

#define STAGE_K(s0v, buf)                                                     \
    do {                                                                      \
        _Pragma("unroll")                                                     \
        for (int i = 0; i < 2; ++i) {                                         \
            int c    = i * 512 + tid;                                         \
            int sr   = c >> 4;                                                \
            int cbs  = ((c & 15) * 16) ^ ((sr & 7) << 4);                     \
            gload_lds16(qkv + kvrow0 + (size_t)((s0v) + sr) * LDQ + D_ + (cbs >> 1), \
                        &Ks[buf][c * 8]);                                     \
        }                                                                     \
    } while (0)

#define LOAD_V(s0v)                                                           \
    do {                                                                      \
        _Pragma("unroll")                                                     \
        for (int it = 0; it < 2; ++it) {                                      \
            int c = it * 512 + tid;                                           \
            int s = c >> 4, dc = c & 15;                                      \
            vr[it] = *reinterpret_cast<const bf16x8*>(                        \
                qkv + kvrow0 + (size_t)((s0v) + s) * LDQ + 2 * D_ + dc * 8);  \
        }                                                                     \
    } while (0)

    STAGE_K(0, 0);
    LOAD_V(0);

    for (int st = 0; st < nst; ++st) {
        const int s0 = st * 64;
        const int cur = st & 1;
        __syncthreads();   // full drain: K(st) in LDS, vr = V(st); orders VsT overwrite

        // scatter V(st) -> VsT (conflict-free: stride 68 + XOR swizzle)
#pragma unroll
        for (int it = 0; it < 2; ++it) {
            int c = it * 512 + tid;
            int s = c >> 4, dc = c & 15;
            int sswz = s ^ ((dc & 15) << 2);
            short* dst = &VsT[(dc * 8) * SV + sswz];
#pragma unroll
            for (int j = 0; j < 8; ++j)
                dst[j * SV] = vr[it][j];
        }
        // prefetch tile st+1 (stays in flight across the barrier below)
        if (st + 1 < nst) {
            STAGE_K(s0 + 64, cur ^ 1);
            LOAD_V(s0 + 64);
        }
        asm volatile("s_waitcnt lgkmcnt(0)" ::: "memory");
        __builtin_amdgcn_s_barrier();
        __builtin_amdgcn_sched_barrier(0);

        // ---- S^T = K Q^T (swapped): sfr[f][i] = S[kv=s0+16f+4hi+i][q=t0+lo]
        f32x4 sfr[4] = {};
        __builtin_amdgcn_s_setprio(1);
#pragma unroll
        for (int f = 0; f < 4; ++f) {
            int srow = f * 16 + lo;
            int sw = (srow & 7) << 4;
#pragma unroll
            for (int dk = 0; dk < 4; ++dk) {
                bf16x8 kf = *reinterpret_cast<const bf16x8*>(
                    (const char*)&Ks[cur][0] + srow * 256 + ((dk * 64 + hi * 16) ^ sw));
                sfr[f] = MFMA32(kf, qf[dk], sfr[f]);
            }
        }
        __builtin_amdgcn_s_setprio(0);

        const float qsc = 0.08838834764831845f;
#pragma unroll
        for (int f = 0; f < 4; ++f)
#pragma unroll
            for (int i = 0; i < 4; ++i)
                sfr[f][i] *= qsc;
        // causal mask on the last two tiles; kv = s0+16f+4hi+i, q = t0+lo
        if (st >= nst - 2) {
#pragma unroll
            for (int f = 0; f < 4; ++f)
#pragma unroll
                for (int i = 0; i < 4; ++i)
                    if (s0 + f * 16 + hi * 4 + i > t0 + lo) sfr[f][i] = -1e30f;
        }

        // ---- online softmax: row q=lo is 16 local values x 4 hi-groups
        float mx = -1e30f;
#pragma unroll
        for (int f = 0; f < 4; ++f)
#pragma unroll
            for (int i = 0; i < 4; ++i)
                mx = fmaxf(mx, sfr[f][i]);
        mx = fmaxf(mx, __shfl_xor(mx, 16));
        mx = fmaxf(mx, __shfl_xor(mx, 32));
        float mn = fmaxf(mreg, mx);
        float ps = __expf(mreg - mn);
        mreg = mn;
        float sum = 0.f;
#pragma unroll
        for (int f = 0; f < 4; ++f)
#pragma unroll
            for (int i = 0; i < 4; ++i) {
                sfr[f][i] = __expf(sfr[f][i] - mn);
                sum += sfr[f][i];
            }
        sum += __shfl_xor(sum, 16);
        sum += __shfl_xor(sum, 32);
        lreg = lreg * ps + sum;

        // rescale octx: octx[f8][i] holds q = hi*4+i -> fetch ps from lane hi*4+i
        float psq[4];
#pragma unroll
        for (int i = 0; i < 4; ++i)
            psq[i] = __shfl(ps, hi * 4 + i);
#pragma unroll
        for (int f8 = 0; f8 < 8; ++f8)
#pragma unroll
            for (int i = 0; i < 4; ++i)
                octx[f8][i] *= psq[i];

        // ---- PV: PA fragment is in-register (sigma layout match)
#pragma unroll
        for (int ks = 0; ks < 2; ++ks) {
            union { bf16x8 v; short s[8]; } pa;
#pragma unroll
            for (int j = 0; j < 4; ++j) {
                pa.s[j]     = f2bf(sfr[2 * ks][j]);
                pa.s[j + 4] = f2bf(sfr[2 * ks + 1][j]);
            }
            __builtin_amdgcn_s_setprio(1);
#pragma unroll
            for (int f8 = 0; f8 < 8; ++f8) {
                int d = f8 * 16 + lo;
                int sw2 = ((d >> 3) & 15) << 2;
                const short* vrow = &VsT[d * SV];
                union { bf16x8 v; uint2 u[2]; } vb;
                vb.u[0] = *reinterpret_cast<const uint2*>(vrow + ((ks * 32 + hi * 4) ^ sw2));
                vb.u[1] = *reinterpret_cast<const uint2*>(vrow + ((ks * 32 + 16 + hi * 4) ^ sw2));
                octx[f8] = MFMA32(pa.v, vb.v, octx[f8]);
            }
            __builtin_amdgcn_s_setprio(0);
        }
    }
#undef STAGE_K
#undef LOAD_V

    // normalize: octx[f8][i] is q = t0+hi*4+i -> lreg from lane hi*4+i
    float linv[4];
#pragma unroll
    for (int i = 0; i < 4; ++i)
        linv[i] = 1.f / __shfl(lreg, hi * 4 + i);
#pragma unroll
    for (int i = 0; i < 4; ++i) {
        size_t rb = (size_t)(b * T_ + t0 + hi * 4 + i) * D_ + h * DH_;
#pragma unroll
        for (int f8 = 0; f8 < 8; ++f8)
            ctx[rb + f8 * 16 + lo] = __float2bfloat16(octx[f8][i] * linv[i]);
    }
}

// ---------------------------------------------------------------------------
extern "C" void kernel_launch(void* const* d_in, const int* in_sizes, int n_in,
                              void* d_out, int out_size, void* d_ws, size_t ws_size,
                              hipStream_t stream)
{
    (void)in_sizes; (void)n_in; (void)out_size; (void)ws_size;
    const float* x   = (const float*)d_in[0];
    const float* lns = (const float*)d_in[1];
    const float* lno = (const float*)d_in[2];
    const float* wq  = (const float*)d_in[3];
    const float* wk  = (const float*)d_in[4];
    const float* wv  = (const float*)d_in[5];
    const float* wo  = (const float*)d_in[6];
    const float* w1  = (const float*)d_in[7];
    const float* b1  = (const float*)d_in[8];
    const float* w2  = (const float*)d_in[9];
    const float* b2  = (const float*)d_in[10];
    float* out = (float*)d_out;

    char* ws = (char*)d_ws;
    __hip_bfloat16* wqkvT = (__hip_bfloat16*)(ws);                 // 6144x2048 bf16
    __hip_bfloat16* woT   = (__hip_bfloat16*)(ws + 25165824);      // 2048x2048
    __hip_bfloat16* w1T   = (__hip_bfloat16*)(ws + 33554432);      // 8192x2048
    __hip_bfloat16* w2T   = (__hip_bfloat16*)(ws + 67108864);      // 2048x8192
    __hip_bfloat16* xn    = (__hip_bfloat16*)(ws + 100663296);     // 4096x2048 (xn / xn2)
    __hip_bfloat16* qkv   = (__hip_bfloat16*)(ws + 117440512);     // 4096x6144
    __hip_bfloat16* hbuf  = qkv;                                   // 4096x8192 (aliases qkv+ctx)
    __hip_bfloat16* ctx   = (__hip_bfloat16*)(ws + 167772160);     // 4096x2048
    float*          x1    = (float*)(ws + 184549376);              // 4096x2048 f32

    transpose_cvt<<<dim3(32, 64),  256, 0, stream>>>(wq, wqkvT, 2048, 2048, 2048, 0);
    transpose_cvt<<<dim3(32, 64),  256, 0, stream>>>(wk, wqkvT, 2048, 2048, 2048, 2048);
    transpose_cvt<<<dim3(32, 64),  256, 0, stream>>>(wv, wqkvT, 2048, 2048, 2048, 4096);
    transpose_cvt<<<dim3(32, 64),  256, 0, stream>>>(wo, woT,   2048, 2048, 2048, 0);
    transpose_cvt<<<dim3(128, 64), 256, 0, stream>>>(w1, w1T,   2048, 8192, 2048, 0);
    transpose_cvt<<<dim3(32, 256), 256, 0, stream>>>(w2, w2T,   8192, 2048, 8192, 0);

    ln_kernel<<<4096, 256, 0, stream>>>(x, lns, lno, xn);
    gemm8p<0, 128><<<dim3(24, 32), 512, 0, stream>>>(xn, wqkvT, qkv, nullptr, nullptr, 4096, 6144, 2048);
    rope_kernel<<<8192, 256, 0, stream>>>(qkv);
    attn_kernel<<<dim3(16, 32), 512, 0, stream>>>(qkv, ctx);
    gemm8p<1, 128><<<dim3(8, 32), 512, 0, stream>>>(ctx, woT, x1, nullptr, x, 4096, 2048, 2048);
    ln_kernel<<<4096, 256, 0, stream>>>(x1, lns, lno, xn);
    gemm8p<2, 256><<<dim3(32, 16), 512, 0, stream>>>(xn, w1T, hbuf, b1, nullptr, 4096, 8192, 2048);
    gemm8p<3, 128><<<dim3(8, 32), 512, 0, stream>>>(hbuf, w2T, out, b2, x1, 4096, 2048, 8192);
}